// Round 9
// baseline (337.612 us; speedup 1.0000x reference)
//
#include <hip/hip_runtime.h>
#include <hip/hip_bf16.h>
#include <math.h>

#define B_  64
#define NS  512
#define NR  256
#define DD  1024
#define NEGV (-1e10f)

typedef __attribute__((ext_vector_type(4))) float f32x4;
typedef __attribute__((ext_vector_type(8))) short bf16x8;

__device__ __forceinline__ unsigned short f2bf(float x) {
    unsigned u = __builtin_bit_cast(unsigned, x);
    unsigned r = u + 0x7FFFu + ((u >> 16) & 1u);
    return (unsigned short)(r >> 16);
}
// packed bf16 convert: D.lo = bf16(x), D.hi = bf16(y)
__device__ __forceinline__ unsigned pk2(float x, float y) {
    unsigned r;
    asm("v_cvt_pk_bf16_f32 %0, %1, %2" : "=v"(r) : "v"(x), "v"(y));
    return r;
}
__device__ __forceinline__ void pk_hilo(float x, float y, unsigned& h, unsigned& l) {
    h = pk2(x, y);
    const float hx = __builtin_bit_cast(float, h << 16);
    const float hy = __builtin_bit_cast(float, h & 0xFFFF0000u);
    l = pk2(x - hx, y - hy);
}
// async global->LDS, 16B per lane
__device__ __forceinline__ void gload16(const void* g, void* l) {
    __builtin_amdgcn_global_load_lds((const __attribute__((address_space(1))) void*)g,
                                     (__attribute__((address_space(3))) void*)l, 16, 0, 0);
}

// ---------------------------------------------------------------- zero ws
__global__ __launch_bounds__(64) void zero_ws(double* ws) {
    if (threadIdx.x == 0) { ws[0] = 0.0; ws[1] = 0.0; }
}

// ================================================================ stage 1 (unchanged: 110us local optimum)
__global__ __launch_bounds__(256) void att_mfma(
    const float* __restrict__ span, const float* __restrict__ image,
    const int* __restrict__ smask, const int* __restrict__ imask,
    float* __restrict__ att, float* __restrict__ rowP, float* __restrict__ colP,
    int doStats) {
    const int b  = blockIdx.z;
    const int s0 = blockIdx.y * 128;
    const int r0 = blockIdx.x * 128;
    __shared__ unsigned short Ah[128][40], Al[128][40], Bh[128][40], Bl[128][40];
    const int tid  = threadIdx.x;
    const int lane = tid & 63;
    const int w    = tid >> 6;
    const int wso  = (w >> 1) * 64;
    const int wro  = (w & 1) * 64;
    const float* Sp = span  + ((size_t)b * NS + s0) * DD;
    const float* Im = image + ((size_t)b * NR + r0) * DD;

    f32x4 acc[4][4];
    #pragma unroll
    for (int i = 0; i < 4; ++i)
        #pragma unroll
        for (int j = 0; j < 4; ++j) acc[i][j] = (f32x4){0.f, 0.f, 0.f, 0.f};

    const int krel = (tid & 7) * 4;   // 0..28
    const int row0 = tid >> 3;        // 0..31
    const int fr   = lane & 15;
    const int fk   = (lane >> 4) * 8;

    for (int k0 = 0; k0 < DD; k0 += 32) {
        #pragma unroll
        for (int p = 0; p < 4; ++p) {
            const int row = row0 + p * 32;
            const float4 a = *reinterpret_cast<const float4*>(Sp + (size_t)row * DD + k0 + krel);
            const float4 c = *reinterpret_cast<const float4*>(Im + (size_t)row * DD + k0 + krel);
            unsigned h0, l0, h1, l1;
            uint2 u;
            pk_hilo(a.x, a.y, h0, l0); pk_hilo(a.z, a.w, h1, l1);
            u.x = h0; u.y = h1; *reinterpret_cast<uint2*>(&Ah[row][krel]) = u;
            u.x = l0; u.y = l1; *reinterpret_cast<uint2*>(&Al[row][krel]) = u;
            pk_hilo(c.x, c.y, h0, l0); pk_hilo(c.z, c.w, h1, l1);
            u.x = h0; u.y = h1; *reinterpret_cast<uint2*>(&Bh[row][krel]) = u;
            u.x = l0; u.y = l1; *reinterpret_cast<uint2*>(&Bl[row][krel]) = u;
        }
        __syncthreads();
        bf16x8 ah[4], al[4], bh[4], bl[4];
        #pragma unroll
        for (int mf = 0; mf < 4; ++mf) {
            ah[mf] = *reinterpret_cast<const bf16x8*>(&Ah[wso + mf * 16 + fr][fk]);
            al[mf] = *reinterpret_cast<const bf16x8*>(&Al[wso + mf * 16 + fr][fk]);
            bh[mf] = *reinterpret_cast<const bf16x8*>(&Bh[wro + mf * 16 + fr][fk]);
            bl[mf] = *reinterpret_cast<const bf16x8*>(&Bl[wro + mf * 16 + fr][fk]);
        }
        #pragma unroll
        for (int mf = 0; mf < 4; ++mf)
            #pragma unroll
            for (int nf = 0; nf < 4; ++nf) {
                acc[mf][nf] = __builtin_amdgcn_mfma_f32_16x16x32_bf16(ah[mf], bh[nf], acc[mf][nf], 0, 0, 0);
                acc[mf][nf] = __builtin_amdgcn_mfma_f32_16x16x32_bf16(ah[mf], bl[nf], acc[mf][nf], 0, 0, 0);
                acc[mf][nf] = __builtin_amdgcn_mfma_f32_16x16x32_bf16(al[mf], bh[nf], acc[mf][nf], 0, 0, 0);
            }
        __syncthreads();
    }

    float* rowLDS = reinterpret_cast<float*>(&Ah[0][0]);
    float* colLDS = rowLDS + 256;
    const int fq = lane >> 4;
    int imv[4];
    #pragma unroll
    for (int nf = 0; nf < 4; ++nf) imv[nf] = imask[b * NR + r0 + wro + nf * 16 + fr];
    float cmax[4] = {-3.4e38f, -3.4e38f, -3.4e38f, -3.4e38f};
    #pragma unroll
    for (int mf = 0; mf < 4; ++mf) {
        #pragma unroll
        for (int i = 0; i < 4; ++i) {
            const int s = s0 + wso + mf * 16 + fq * 4 + i;
            const int sm = smask[b * NS + s];
            float* orow = att + ((size_t)b * NS + s) * NR + r0 + wro;
            float vj[4];
            #pragma unroll
            for (int nf = 0; nf < 4; ++nf) {
                float v = acc[mf][nf][i] * (float)(sm * imv[nf]);
                v = (v != 0.0f) ? v : NEGV;
                orow[nf * 16 + fr] = v;
                vj[nf] = v;
                cmax[nf] = fmaxf(cmax[nf], v);
            }
            if (doStats) {
                float rm = fmaxf(fmaxf(vj[0], vj[1]), fmaxf(vj[2], vj[3]));
                rm = fmaxf(rm, __shfl_xor(rm, 1));
                rm = fmaxf(rm, __shfl_xor(rm, 2));
                rm = fmaxf(rm, __shfl_xor(rm, 4));
                rm = fmaxf(rm, __shfl_xor(rm, 8));
                if (fr == 0) rowLDS[(wso + mf * 16 + fq * 4 + i) * 2 + (w & 1)] = rm;
            }
        }
    }
    if (doStats) {
        #pragma unroll
        for (int nf = 0; nf < 4; ++nf) {
            cmax[nf] = fmaxf(cmax[nf], __shfl_xor(cmax[nf], 16));
            cmax[nf] = fmaxf(cmax[nf], __shfl_xor(cmax[nf], 32));
        }
        if (lane < 16) {
            #pragma unroll
            for (int nf = 0; nf < 4; ++nf)
                colLDS[(wro + nf * 16 + lane) * 2 + (w >> 1)] = cmax[nf];
        }
        __syncthreads();
        if (tid < 128) {
            rowP[((size_t)b * NS + s0 + tid) * 2 + blockIdx.x] =
                fmaxf(rowLDS[tid * 2 + 0], rowLDS[tid * 2 + 1]);
        } else {
            const int c = tid - 128;
            colP[((size_t)b * NR + r0 + c) * 4 + blockIdx.y] =
                fmaxf(colLDS[c * 2 + 0], colLDS[c * 2 + 1]);
        }
    }
}

// ================================================================ combine partial maxes -> m1 (rows), m2 (cols)
__global__ __launch_bounds__(256) void combine_max(
    const float* __restrict__ rowP, const float* __restrict__ colP,
    float* __restrict__ m1, float* __restrict__ m2) {
    const int idx = blockIdx.x * 256 + threadIdx.x;
    if (idx < B_ * NS) {
        m1[idx] = fmaxf(rowP[(size_t)idx * 2 + 0], rowP[(size_t)idx * 2 + 1]);
    } else if (idx < B_ * NS + B_ * NR) {
        const int j = idx - B_ * NS;
        m2[j] = fmaxf(fmaxf(colP[(size_t)j * 4 + 0], colP[(size_t)j * 4 + 1]),
                      fmaxf(colP[(size_t)j * 4 + 2], colP[(size_t)j * 4 + 3]));
    }
}

// ================================================================ transpose f32 -> bf16
// MODE 0: 64-chunk swizzle pos = (k&~63) + ((k&63) ^ ((d&7)<<3))       (spT, gemm2)
// MODE 1: 32-chunk swizzle pos = (k&~31) + ((((k>>3)&3)^((d>>1)&3))<<3) + (k&7)   (imgT, gemm1)
template<int MODE>
__global__ __launch_bounds__(256) void transpose_swz(
    const float* __restrict__ src, unsigned short* __restrict__ dst, int N) {
    const int b = blockIdx.z, n0 = blockIdx.y * 32, d0 = blockIdx.x * 32;
    __shared__ unsigned short T[32][36];
    const int t = threadIdx.x;
    {
        const int n = t >> 3, dq = (t & 7) * 4;
        const float4 v = *reinterpret_cast<const float4*>(src + ((size_t)b * N + n0 + n) * DD + d0 + dq);
        T[dq + 0][n] = f2bf(v.x); T[dq + 1][n] = f2bf(v.y);
        T[dq + 2][n] = f2bf(v.z); T[dq + 3][n] = f2bf(v.w);
    }
    __syncthreads();
    {
        const int d = t >> 3, nq = (t & 7) * 4;
        const int dg = d0 + d;
        const int k = n0 + nq;
        int pos;
        if constexpr (MODE == 0) {
            pos = (k & ~63) + ((k & 63) ^ ((dg & 7) << 3));
        } else {
            pos = (k & ~31) + (((((k >> 3) & 3) ^ ((dg >> 1) & 3)) << 3) | (k & 7));
        }
        const size_t idx = ((size_t)b * DD + dg) * N + pos;
        *reinterpret_cast<ushort4*>(dst + idx) = *reinterpret_cast<const ushort4*>(&T[d][nq]);
    }
}

// ================================================================ gemm1 fused (restructured): full-K, A staged once.
// Block = (m-tile 32 rows, batch). id = mt*64 + b  (same-b blocks -> same XCD).
// A (w1, 32x256 bf16) staged once from att (exp + rowsum); B (imgT) streamed
// per (dc, kcc) via linear gload16 from 32-chunk pre-swizzled global.
__global__ __launch_bounds__(256) void gemm1_fused(
    const float* __restrict__ att, const unsigned short* __restrict__ imgT,
    const float* __restrict__ span,
    const int* __restrict__ smask, const int* __restrict__ imask,
    const float* __restrict__ m1,
    float* __restrict__ att_first, double* __restrict__ wsum) {
    const int id = blockIdx.x;
    const int b  = id & 63;
    const int m0 = (id >> 6) * 32;
    __shared__ unsigned short As[32 * 256];   // 16KB: [row][256] swizzled granules
    __shared__ unsigned short Bs[256 * 32];   // 16KB: [d_rel][32] linear (global pre-swz)
    __shared__ float ims[256];
    __shared__ float m1s[32], sms[32], rowsumS[32];
    __shared__ float redsum[256];
    const int tid = threadIdx.x, lane = tid & 63, w = tid >> 6;
    const int fr = lane & 15, fq = lane >> 4;
    ims[tid] = (float)imask[b * NR + tid];
    if (tid < 32) {
        m1s[tid] = m1[b * NS + m0 + tid];
        sms[tid] = (float)smask[b * NS + m0 + tid];
    }
    __syncthreads();

    // ---- A-stage (once): exp(att - m1) -> bf16 swizzled; rowsum
    const int arow = tid >> 3, cg = tid & 7;
    {
        const float* ap = att + ((size_t)b * NS + m0 + arow) * NR + cg * 32;
        const float m1v = m1s[arow];
        float rsum = 0.0f;
        #pragma unroll
        for (int gg = 0; gg < 4; ++gg) {
            const float4 a0 = *reinterpret_cast<const float4*>(ap + gg * 8);
            const float4 a1 = *reinterpret_cast<const float4*>(ap + gg * 8 + 4);
            const float e0 = __expf(a0.x - m1v), e1 = __expf(a0.y - m1v);
            const float e2 = __expf(a0.z - m1v), e3 = __expf(a0.w - m1v);
            const float e4 = __expf(a1.x - m1v), e5 = __expf(a1.y - m1v);
            const float e6 = __expf(a1.z - m1v), e7 = __expf(a1.w - m1v);
            rsum += (e0 + e1 + e2 + e3) + (e4 + e5 + e6 + e7);
            const int kb = cg * 32 + gg * 8;
            uint4 u;
            u.x = pk2(e0 * ims[kb + 0], e1 * ims[kb + 1]);
            u.y = pk2(e2 * ims[kb + 2], e3 * ims[kb + 3]);
            u.z = pk2(e4 * ims[kb + 4], e5 * ims[kb + 5]);
            u.w = pk2(e6 * ims[kb + 6], e7 * ims[kb + 7]);
            const int g = cg * 4 + gg;
            *reinterpret_cast<uint4*>(&As[arow * 256 + ((g ^ (arow & 7)) << 3)]) = u;
        }
        rsum += __shfl_xor(rsum, 1);
        rsum += __shfl_xor(rsum, 2);
        rsum += __shfl_xor(rsum, 4);
        if ((tid & 7) == 0) rowsumS[arow] = rsum;
    }
    __syncthreads();

    float sumsq = 0.0f;
    const int brow = tid >> 2;            // B staging row within 64-group
    const int bcol = (tid & 3) * 8;       // B staging col (shorts)
    for (int dc = 0; dc < 4; ++dc) {
        const int d0 = dc * 256;
        f32x4 acc[2][4];
        #pragma unroll
        for (int i = 0; i < 2; ++i)
            #pragma unroll
            for (int j = 0; j < 4; ++j) acc[i][j] = (f32x4){0.f, 0.f, 0.f, 0.f};
        for (int kcc = 0; kcc < 8; ++kcc) {
            const unsigned short* bsrc = imgT + ((size_t)b * DD + d0) * NR + kcc * 32;
            #pragma unroll
            for (int c = 0; c < 4; ++c)
                gload16(bsrc + (size_t)(c * 64 + brow) * NR + bcol,
                        (char*)Bs + c * 4096 + tid * 16);
            __syncthreads();
            bf16x8 aF[2], bF[4];
            #pragma unroll
            for (int mf = 0; mf < 2; ++mf) {
                const int row = mf * 16 + fr;
                aF[mf] = *reinterpret_cast<const bf16x8*>(
                    &As[row * 256 + (((kcc * 4 + fq) ^ (row & 7)) << 3)]);
            }
            #pragma unroll
            for (int nf = 0; nf < 4; ++nf) {
                const int dr = w * 64 + nf * 16 + fr;
                bF[nf] = *reinterpret_cast<const bf16x8*>(
                    &Bs[dr * 32 + ((fq ^ ((dr >> 1) & 3)) << 3)]);
            }
            #pragma unroll
            for (int mf = 0; mf < 2; ++mf)
                #pragma unroll
                for (int nf = 0; nf < 4; ++nf)
                    acc[mf][nf] = __builtin_amdgcn_mfma_f32_16x16x32_bf16(aF[mf], bF[nf], acc[mf][nf], 0, 0, 0);
            __syncthreads();
        }
        // epilogue for this d-chunk: normalize + write + MSE
        #pragma unroll
        for (int mf = 0; mf < 2; ++mf) {
            #pragma unroll
            for (int i = 0; i < 4; ++i) {
                const int row = mf * 16 + fq * 4 + i;
                const float fac = sms[row] / rowsumS[row];
                const size_t base = ((size_t)b * NS + m0 + row) * DD + d0 + w * 64;
                #pragma unroll
                for (int nf = 0; nf < 4; ++nf) {
                    const float v = acc[mf][nf][i] * fac;
                    const float rv = span[base + nf * 16 + fr];
                    att_first[base + nf * 16 + fr] = v;
                    const float dx = rv - v;
                    sumsq += dx * dx;
                }
            }
        }
    }
    redsum[tid] = sumsq; __syncthreads();
    for (int off = 128; off; off >>= 1) {
        if (tid < off) redsum[tid] += redsum[tid + off];
        __syncthreads();
    }
    if (tid == 0) atomicAdd(wsum, (double)redsum[0]);
}

// ================================================================ gemm2 fused (unchanged): att_second = softmax-col(att)^T @ span (MSE only)
__global__ __launch_bounds__(256) void gemm2_fused(
    const float* __restrict__ att, const unsigned short* __restrict__ spT,
    const float* __restrict__ image,
    const int* __restrict__ smask, const int* __restrict__ imask,
    const float* __restrict__ m2, double* __restrict__ wsum) {
    const int b = blockIdx.z, r0 = blockIdx.y * 64, d0 = blockIdx.x * 256;
    __shared__ unsigned short As[64 * 64];
    __shared__ unsigned short Bs[256 * 64];
    __shared__ float redsum[256];
    __shared__ float m2s[64], imsv[64], colsumS[64];
    __shared__ float smsK[512];
    __shared__ float cs4[4][64];
    const int tid = threadIdx.x, lane = tid & 63, w = tid >> 6;
    const int fr = lane & 15, fq = lane >> 4;
    if (tid < 64) {
        m2s[tid] = m2[b * NR + r0 + tid];
        imsv[tid] = (float)imask[b * NR + r0 + tid];
    }
    smsK[tid]       = (float)smask[b * NS + tid];
    smsK[tid + 256] = (float)smask[b * NS + 256 + tid];
    f32x4 acc[4][4];
    #pragma unroll
    for (int i = 0; i < 4; ++i)
        #pragma unroll
        for (int j = 0; j < 4; ++j) acc[i][j] = (f32x4){0.f, 0.f, 0.f, 0.f};

    const int asr = tid >> 2;
    const int arg = (tid & 3) * 16;
    const int srow = tid >> 3;
    const int scol = (tid & 7) * 16;
    float csum[16];
    #pragma unroll
    for (int j = 0; j < 16; ++j) csum[j] = 0.0f;
    __syncthreads();

    for (int kc = 0; kc < NS / 64; ++kc) {
        const char* bsrc = (const char*)(spT + ((size_t)b * DD + d0) * NS) + kc * 128 + scol;
        #pragma unroll
        for (int c = 0; c < 8; ++c)
            gload16(bsrc + (size_t)(c * 32 + srow) * (NS * 2), (char*)Bs + (c * 256 + tid) * 16);
        {
            const float* ap = att + ((size_t)b * NS + kc * 64 + asr) * NR + r0 + arg;
            const float smv = smsK[kc * 64 + asr];
            const float4 a0 = *reinterpret_cast<const float4*>(ap);
            const float4 a1 = *reinterpret_cast<const float4*>(ap + 4);
            const float4 a2 = *reinterpret_cast<const float4*>(ap + 8);
            const float4 a3 = *reinterpret_cast<const float4*>(ap + 12);
            const float av[16] = {a0.x, a0.y, a0.z, a0.w, a1.x, a1.y, a1.z, a1.w,
                                  a2.x, a2.y, a2.z, a2.w, a3.x, a3.y, a3.z, a3.w};
            const int slo = asr & 7;
            const int shi = asr >> 3;
            #pragma unroll
            for (int j = 0; j < 16; ++j) {
                const int r = arg + j;
                const float e = __expf(av[j] - m2s[r]);
                csum[j] += e;
                const int pos = slo | ((shi ^ (r & 7)) << 3);
                As[r * 64 + pos] = f2bf(e * smv);
            }
        }
        __syncthreads();
        #pragma unroll
        for (int ks = 0; ks < 2; ++ks) {
            bf16x8 aF[4], bF[4];
            #pragma unroll
            for (int mf = 0; mf < 4; ++mf) {
                const int row = mf * 16 + fr;
                const int pos = (ks * 32 + fq * 8) ^ ((row & 7) << 3);
                aF[mf] = *reinterpret_cast<const bf16x8*>(&As[row * 64 + pos]);
            }
            #pragma unroll
            for (int nf = 0; nf < 4; ++nf) {
                const int row = w * 64 + nf * 16 + fr;
                const int pos = (ks * 32 + fq * 8) ^ ((row & 7) << 3);
                bF[nf] = *reinterpret_cast<const bf16x8*>(&Bs[row * 64 + pos]);
            }
            #pragma unroll
            for (int mf = 0; mf < 4; ++mf)
                #pragma unroll
                for (int nf = 0; nf < 4; ++nf)
                    acc[mf][nf] = __builtin_amdgcn_mfma_f32_16x16x32_bf16(aF[mf], bF[nf], acc[mf][nf], 0, 0, 0);
        }
        __syncthreads();
    }
    #pragma unroll
    for (int j = 0; j < 16; ++j) {
        float v = csum[j];
        v += __shfl_xor(v, 4);
        v += __shfl_xor(v, 8);
        v += __shfl_xor(v, 16);
        v += __shfl_xor(v, 32);
        if (lane < 4) cs4[w][lane * 16 + j] = v;
    }
    __syncthreads();
    if (tid < 64) colsumS[tid] = (cs4[0][tid] + cs4[1][tid]) + (cs4[2][tid] + cs4[3][tid]);
    __syncthreads();

    float sumsq = 0.0f;
    #pragma unroll
    for (int mf = 0; mf < 4; ++mf) {
        #pragma unroll
        for (int i = 0; i < 4; ++i) {
            const int row = mf * 16 + fq * 4 + i;
            const float fac = imsv[row] / colsumS[row];
            const size_t base = ((size_t)b * NR + r0 + row) * DD + d0 + w * 64;
            #pragma unroll
            for (int nf = 0; nf < 4; ++nf) {
                const float dx = image[base + nf * 16 + fr] - acc[mf][nf][i] * fac;
                sumsq += dx * dx;
            }
        }
    }
    redsum[tid] = sumsq; __syncthreads();
    for (int off = 128; off; off >>= 1) {
        if (tid < off) redsum[tid] += redsum[tid + off];
        __syncthreads();
    }
    if (tid == 0) atomicAdd(wsum + 1, (double)redsum[0]);
}

// ================================================================ fallback f32 kernels (used when ws too small)
__global__ __launch_bounds__(256) void first_kernel(
    const float* __restrict__ span, const float* __restrict__ image,
    const int* __restrict__ smask, const int* __restrict__ imask,
    const float* __restrict__ att, float* __restrict__ att_first,
    double* __restrict__ ws) {
    const int b  = blockIdx.y;
    const int s0 = blockIdx.x * 32;
    __shared__ float wT[256][36];
    __shared__ float Is[32][132];
    __shared__ float red[256];
    const int tid  = threadIdx.x;
    const int lane = tid & 63, wave = tid >> 6;
    for (int i = 0; i < 8; ++i) {
        const int srel = wave * 8 + i;
        const int s    = s0 + srel;
        const float4 v = *reinterpret_cast<const float4*>(att + ((size_t)b * NS + s) * NR + lane * 4);
        float m = fmaxf(fmaxf(v.x, v.y), fmaxf(v.z, v.w));
        #pragma unroll
        for (int off = 32; off; off >>= 1) m = fmaxf(m, __shfl_xor(m, off));
        float4 e;
        e.x = expf(v.x - m); e.y = expf(v.y - m); e.z = expf(v.z - m); e.w = expf(v.w - m);
        float sum = e.x + e.y + e.z + e.w;
        #pragma unroll
        for (int off = 32; off; off >>= 1) sum += __shfl_xor(sum, off);
        const float fac = (float)smask[b * NS + s] / sum;
        const int4 im4 = *reinterpret_cast<const int4*>(imask + b * NR + lane * 4);
        wT[lane * 4 + 0][srel] = e.x * fac * (float)im4.x;
        wT[lane * 4 + 1][srel] = e.y * fac * (float)im4.y;
        wT[lane * 4 + 2][srel] = e.z * fac * (float)im4.z;
        wT[lane * 4 + 3][srel] = e.w * fac * (float)im4.w;
    }
    __syncthreads();
    float sumsq = 0.0f;
    const int txd = tid & 31;
    const int tys = tid >> 5;
    const float* Ib = image + (size_t)b * NR * DD;
    for (int dc = 0; dc < 8; ++dc) {
        const int d0 = dc * 128;
        float acc[4][4] = {};
        for (int rc = 0; rc < 8; ++rc) {
            const int r0 = rc * 32;
            {
                const int rr = tid >> 3;
                const int cb = tid & 7;
                const float* src = Ib + (size_t)(r0 + rr) * DD + d0;
                #pragma unroll
                for (int q = 0; q < 4; ++q)
                    *reinterpret_cast<float4*>(&Is[rr][(cb + 8 * q) * 4]) =
                        *reinterpret_cast<const float4*>(src + (cb + 8 * q) * 4);
            }
            __syncthreads();
            #pragma unroll 4
            for (int rr = 0; rr < 32; ++rr) {
                const float4 wv = *reinterpret_cast<const float4*>(&wT[r0 + rr][tys * 4]);
                const float4 iv = *reinterpret_cast<const float4*>(&Is[rr][txd * 4]);
                const float wvv[4] = {wv.x, wv.y, wv.z, wv.w};
                const float ivv[4] = {iv.x, iv.y, iv.z, iv.w};
                #pragma unroll
                for (int i = 0; i < 4; ++i)
                    #pragma unroll
                    for (int j = 0; j < 4; ++j)
                        acc[i][j] += wvv[i] * ivv[j];
            }
            __syncthreads();
        }
        #pragma unroll
        for (int i = 0; i < 4; ++i) {
            const int s = s0 + tys * 4 + i;
            const size_t base = ((size_t)b * NS + s) * DD + d0 + txd * 4;
            const float4 af = {acc[i][0], acc[i][1], acc[i][2], acc[i][3]};
            *reinterpret_cast<float4*>(att_first + base) = af;
            const float4 sp = *reinterpret_cast<const float4*>(span + base);
            float dx;
            dx = sp.x - af.x; sumsq += dx * dx;
            dx = sp.y - af.y; sumsq += dx * dx;
            dx = sp.z - af.z; sumsq += dx * dx;
            dx = sp.w - af.w; sumsq += dx * dx;
        }
    }
    red[tid] = sumsq; __syncthreads();
    for (int off = 128; off; off >>= 1) {
        if (tid < off) red[tid] += red[tid + off];
        __syncthreads();
    }
    if (tid == 0) atomicAdd(ws, (double)red[0]);
}

__global__ __launch_bounds__(256) void second_kernel(
    const float* __restrict__ span, const float* __restrict__ image,
    const int* __restrict__ smask, const int* __restrict__ imask,
    const float* __restrict__ att, double* __restrict__ ws) {
    const int b  = blockIdx.y;
    const int r0 = blockIdx.x * 32;
    __shared__ float w2s[32][36];
    __shared__ float Ss[32][132];
    __shared__ float mArr[32], fArr[32];
    __shared__ float redm[8][32];
    __shared__ float red[256];
    const int tid = threadIdx.x;
    const int rr = tid & 31, q = tid >> 5;
    const float* attb = att + (size_t)b * NS * NR + r0 + rr;
    float mloc = -3.4e38f;
    for (int t = 0; t < 64; ++t)
        mloc = fmaxf(mloc, attb[(size_t)(q * 64 + t) * NR]);
    redm[q][rr] = mloc;
    __syncthreads();
    if (tid < 32) {
        float m = redm[0][tid];
        #pragma unroll
        for (int qq = 1; qq < 8; ++qq) m = fmaxf(m, redm[qq][tid]);
        mArr[tid] = m;
    }
    __syncthreads();
    const float mcol = mArr[rr];
    float sloc = 0.0f;
    for (int t = 0; t < 64; ++t)
        sloc += expf(attb[(size_t)(q * 64 + t) * NR] - mcol);
    redm[q][rr] = sloc;
    __syncthreads();
    if (tid < 32) {
        float s = 0.0f;
        #pragma unroll
        for (int qq = 0; qq < 8; ++qq) s += redm[qq][tid];
        fArr[tid] = (float)imask[b * NR + r0 + tid] / s;
    }
    __syncthreads();
    float sumsq = 0.0f;
    const int txd = tid & 31;
    const int tyr = tid >> 5;
    const float* Sb = span + (size_t)b * NS * DD;
    for (int dc = 0; dc < 8; ++dc) {
        const int d0 = dc * 128;
        float acc[4][4] = {};
        for (int sc = 0; sc < 16; ++sc) {
            const int sb0 = sc * 32;
            {
                const int sr = tid >> 3;
                const int cb = tid & 7;
                const float* src = Sb + (size_t)(sb0 + sr) * DD + d0;
                #pragma unroll
                for (int qq = 0; qq < 4; ++qq)
                    *reinterpret_cast<float4*>(&Ss[sr][(cb + 8 * qq) * 4]) =
                        *reinterpret_cast<const float4*>(src + (cb + 8 * qq) * 4);
            }
            {
                const int ss = tid >> 3;
                const int rq = (tid & 7) * 4;
                const int s  = sb0 + ss;
                const float4 v = *reinterpret_cast<const float4*>(att + ((size_t)b * NS + s) * NR + r0 + rq);
                const float smv = (float)smask[b * NS + s];
                float4 wv;
                wv.x = expf(v.x - mArr[rq + 0]) * fArr[rq + 0] * smv;
                wv.y = expf(v.y - mArr[rq + 1]) * fArr[rq + 1] * smv;
                wv.z = expf(v.z - mArr[rq + 2]) * fArr[rq + 2] * smv;
                wv.w = expf(v.w - mArr[rq + 3]) * fArr[rq + 3] * smv;
                *reinterpret_cast<float4*>(&w2s[ss][rq]) = wv;
            }
            __syncthreads();
            #pragma unroll 4
            for (int ss = 0; ss < 32; ++ss) {
                const float4 wv = *reinterpret_cast<const float4*>(&w2s[ss][tyr * 4]);
                const float4 sv = *reinterpret_cast<const float4*>(&Ss[ss][txd * 4]);
                const float wvv[4] = {wv.x, wv.y, wv.z, wv.w};
                const float svv[4] = {sv.x, sv.y, sv.z, sv.w};
                #pragma unroll
                for (int i = 0; i < 4; ++i)
                    #pragma unroll
                    for (int j = 0; j < 4; ++j)
                        acc[i][j] += wvv[i] * svv[j];
            }
            __syncthreads();
        }
        #pragma unroll
        for (int i = 0; i < 4; ++i) {
            const int r = r0 + tyr * 4 + i;
            const float4 iv = *reinterpret_cast<const float4*>(image + ((size_t)b * NR + r) * DD + d0 + txd * 4);
            float dx;
            dx = iv.x - acc[i][0]; sumsq += dx * dx;
            dx = iv.y - acc[i][1]; sumsq += dx * dx;
            dx = iv.z - acc[i][2]; sumsq += dx * dx;
            dx = iv.w - acc[i][3]; sumsq += dx * dx;
        }
    }
    red[tid] = sumsq; __syncthreads();
    for (int off = 128; off; off >>= 1) {
        if (tid < off) red[tid] += red[tid + off];
        __syncthreads();
    }
    if (tid == 0) atomicAdd(ws + 1, (double)red[0]);
}

// ---------------------------------------------------------------- final score
__global__ __launch_bounds__(64) void score_kernel(const double* __restrict__ ws, float* __restrict__ out) {
    if (threadIdx.x == 0) {
        out[0] = (float)(ws[0] / (double)((size_t)B_ * NS * DD) +
                         ws[1] / (double)((size_t)B_ * NR * DD));
    }
}

extern "C" void kernel_launch(void* const* d_in, const int* in_sizes, int n_in,
                              void* d_out, int out_size, void* d_ws, size_t ws_size,
                              hipStream_t stream) {
    const float* span  = (const float*)d_in[0];
    const float* image = (const float*)d_in[1];
    const int*   smask = (const int*)d_in[2];
    const int*   imask = (const int*)d_in[3];
    float* out       = (float*)d_out;
    float* att_first = out + 1;
    float* att       = out + 1 + (size_t)B_ * NS * DD;

    // ws layout:
    //  wsum(512B) | m1 (B*NS) | m2 (B*NR) | rowP (B*NS*2) | colP (B*NR*4)  (f32)
    //  | X0: imgT (33.5M) for gemm1, then spT (67.1M) overwrites for gemm2
    char* base = (char*)d_ws;
    double* wsum = (double*)base;
    float* m1   = (float*)(base + 512);
    float* m2   = m1 + (size_t)B_ * NS;
    float* rowP = m2 + (size_t)B_ * NR;
    float* colP = rowP + (size_t)B_ * NS * 2;
    char* X0 = (char*)(colP + (size_t)B_ * NR * 4);
    unsigned short* imgT = (unsigned short*)X0;
    unsigned short* spT  = (unsigned short*)X0;
    const size_t NEED = (size_t)(X0 - base) + (size_t)B_ * DD * NS * 2;
    const int wsok = (ws_size >= NEED) ? 1 : 0;

    zero_ws<<<dim3(1), dim3(64), 0, stream>>>(wsum);
    att_mfma<<<dim3(NR / 128, NS / 128, B_), dim3(256), 0, stream>>>(
        span, image, smask, imask, att, rowP, colP, wsok);

    if (wsok) {
        combine_max<<<dim3((B_ * NS + B_ * NR) / 256), dim3(256), 0, stream>>>(
            rowP, colP, m1, m2);
        transpose_swz<1><<<dim3(DD / 32, NR / 32, B_), dim3(256), 0, stream>>>(image, imgT, NR);
        gemm1_fused<<<dim3((NS / 32) * B_), dim3(256), 0, stream>>>(
            att, imgT, span, smask, imask, m1, att_first, wsum);
        transpose_swz<0><<<dim3(DD / 32, NS / 32, B_), dim3(256), 0, stream>>>(span, spT, NS);
        gemm2_fused<<<dim3(DD / 256, NR / 64, B_), dim3(256), 0, stream>>>(
            att, spT, image, smask, imask, m2, wsum);
    } else {
        first_kernel<<<dim3(NS / 32, B_), dim3(256), 0, stream>>>(span, image, smask, imask, att, att_first, wsum);
        second_kernel<<<dim3(NR / 32, B_), dim3(256), 0, stream>>>(span, image, smask, imask, att, wsum);
    }
    score_kernel<<<dim3(1), dim3(64), 0, stream>>>(wsum, out);
}

// Round 10
// 318.552 us; speedup vs baseline: 1.0598x; 1.0598x over previous
//
#include <hip/hip_runtime.h>
#include <hip/hip_bf16.h>
#include <math.h>

#define B_  64
#define NS  512
#define NR  256
#define DD  1024
#define NEGV (-1e10f)

typedef __attribute__((ext_vector_type(4))) float f32x4;
typedef __attribute__((ext_vector_type(8))) short bf16x8;

__device__ __forceinline__ unsigned short f2bf(float x) {
    unsigned u = __builtin_bit_cast(unsigned, x);
    unsigned r = u + 0x7FFFu + ((u >> 16) & 1u);
    return (unsigned short)(r >> 16);
}
// packed bf16 convert: D.lo = bf16(x), D.hi = bf16(y)
__device__ __forceinline__ unsigned pk2(float x, float y) {
    unsigned r;
    asm("v_cvt_pk_bf16_f32 %0, %1, %2" : "=v"(r) : "v"(x), "v"(y));
    return r;
}
__device__ __forceinline__ void pk_hilo(float x, float y, unsigned& h, unsigned& l) {
    h = pk2(x, y);
    const float hx = __builtin_bit_cast(float, h << 16);
    const float hy = __builtin_bit_cast(float, h & 0xFFFF0000u);
    l = pk2(x - hx, y - hy);
}
// async global->LDS, 16B per lane
__device__ __forceinline__ void gload16(const void* g, void* l) {
    __builtin_amdgcn_global_load_lds((const __attribute__((address_space(1))) void*)g,
                                     (__attribute__((address_space(3))) void*)l, 16, 0, 0);
}

// ---------------------------------------------------------------- zero ws
__global__ __launch_bounds__(64) void zero_ws(double* ws) {
    if (threadIdx.x == 0) { ws[0] = 0.0; ws[1] = 0.0; }
}

// ================================================================ stage 1
// att = masked span @ image^T, bf16 hi/lo 3-pass MFMA, 128x128 tile.
// r3 loop schedule, now 512 threads / 8 waves (wave = 64s x 32r) to double
// waves/CU (grid-limited occupancy was the bottleneck: 2 blk/CU, 2 waves/SIMD).
// Full exp softmax partial stats in epilogue (feeds r4 combine_stats).
__global__ __launch_bounds__(512) void att_mfma(
    const float* __restrict__ span, const float* __restrict__ image,
    const int* __restrict__ smask, const int* __restrict__ imask,
    float* __restrict__ att, float2* __restrict__ rowP, float2* __restrict__ colP,
    int doStats) {
    const int b  = blockIdx.z;
    const int s0 = blockIdx.y * 128;
    const int r0 = blockIdx.x * 128;
    __shared__ unsigned short Ah[128][40], Al[128][40], Bh[128][40], Bl[128][40]; // 40KB
    const int tid  = threadIdx.x;
    const int lane = tid & 63;
    const int w    = tid >> 6;        // 0..7
    const int wso  = (w >> 2) * 64;   // s-half
    const int wro  = (w & 3) * 32;    // r-quarter
    const float* Sp = span  + ((size_t)b * NS + s0) * DD;
    const float* Im = image + ((size_t)b * NR + r0) * DD;

    f32x4 acc[4][2];
    #pragma unroll
    for (int i = 0; i < 4; ++i)
        #pragma unroll
        for (int j = 0; j < 2; ++j) acc[i][j] = (f32x4){0.f, 0.f, 0.f, 0.f};

    const int row0 = tid >> 2;        // 0..127 (one row per thread)
    const int kq   = (tid & 3) * 8;   // 0,8,16,24
    const int fr   = lane & 15;
    const int fq   = lane >> 4;
    const int fk   = fq * 8;

    for (int k0 = 0; k0 < DD; k0 += 32) {
        {
            const float4 a0 = *reinterpret_cast<const float4*>(Sp + (size_t)row0 * DD + k0 + kq);
            const float4 a1 = *reinterpret_cast<const float4*>(Sp + (size_t)row0 * DD + k0 + kq + 4);
            const float4 c0 = *reinterpret_cast<const float4*>(Im + (size_t)row0 * DD + k0 + kq);
            const float4 c1 = *reinterpret_cast<const float4*>(Im + (size_t)row0 * DD + k0 + kq + 4);
            unsigned h0, l0, h1, l1, h2, l2, h3, l3;
            uint4 u;
            pk_hilo(a0.x, a0.y, h0, l0); pk_hilo(a0.z, a0.w, h1, l1);
            pk_hilo(a1.x, a1.y, h2, l2); pk_hilo(a1.z, a1.w, h3, l3);
            u.x = h0; u.y = h1; u.z = h2; u.w = h3;
            *reinterpret_cast<uint4*>(&Ah[row0][kq]) = u;
            u.x = l0; u.y = l1; u.z = l2; u.w = l3;
            *reinterpret_cast<uint4*>(&Al[row0][kq]) = u;
            pk_hilo(c0.x, c0.y, h0, l0); pk_hilo(c0.z, c0.w, h1, l1);
            pk_hilo(c1.x, c1.y, h2, l2); pk_hilo(c1.z, c1.w, h3, l3);
            u.x = h0; u.y = h1; u.z = h2; u.w = h3;
            *reinterpret_cast<uint4*>(&Bh[row0][kq]) = u;
            u.x = l0; u.y = l1; u.z = l2; u.w = l3;
            *reinterpret_cast<uint4*>(&Bl[row0][kq]) = u;
        }
        __syncthreads();
        bf16x8 ah[4], al[4], bh[2], bl[2];
        #pragma unroll
        for (int mf = 0; mf < 4; ++mf) {
            ah[mf] = *reinterpret_cast<const bf16x8*>(&Ah[wso + mf * 16 + fr][fk]);
            al[mf] = *reinterpret_cast<const bf16x8*>(&Al[wso + mf * 16 + fr][fk]);
        }
        #pragma unroll
        for (int nf = 0; nf < 2; ++nf) {
            bh[nf] = *reinterpret_cast<const bf16x8*>(&Bh[wro + nf * 16 + fr][fk]);
            bl[nf] = *reinterpret_cast<const bf16x8*>(&Bl[wro + nf * 16 + fr][fk]);
        }
        #pragma unroll
        for (int mf = 0; mf < 4; ++mf)
            #pragma unroll
            for (int nf = 0; nf < 2; ++nf) {
                acc[mf][nf] = __builtin_amdgcn_mfma_f32_16x16x32_bf16(ah[mf], bh[nf], acc[mf][nf], 0, 0, 0);
                acc[mf][nf] = __builtin_amdgcn_mfma_f32_16x16x32_bf16(ah[mf], bl[nf], acc[mf][nf], 0, 0, 0);
                acc[mf][nf] = __builtin_amdgcn_mfma_f32_16x16x32_bf16(al[mf], bh[nf], acc[mf][nf], 0, 0, 0);
            }
        __syncthreads();
    }

    // ---- epilogue: mask + zero->NEG store + fused exp softmax partial stats
    float2* rowLDS = reinterpret_cast<float2*>(&Ah[0][0]);   // [128][4]
    float2* colLDS = rowLDS + 512;                           // [128][2]
    int imv[2];
    #pragma unroll
    for (int nf = 0; nf < 2; ++nf) imv[nf] = imask[b * NR + r0 + wro + nf * 16 + fr];
    float cmax[2] = {-3.4e38f, -3.4e38f};
    float smv[4][4];
    #pragma unroll
    for (int mf = 0; mf < 4; ++mf) {
        #pragma unroll
        for (int i = 0; i < 4; ++i) {
            const int s = s0 + wso + mf * 16 + fq * 4 + i;
            const int sm = smask[b * NS + s];
            smv[mf][i] = (float)sm;
            float* orow = att + ((size_t)b * NS + s) * NR + r0 + wro;
            float vj[2];
            #pragma unroll
            for (int nf = 0; nf < 2; ++nf) {
                float v = acc[mf][nf][i] * (float)(sm * imv[nf]);
                v = (v != 0.0f) ? v : NEGV;
                orow[nf * 16 + fr] = v;
                vj[nf] = v;
                cmax[nf] = fmaxf(cmax[nf], v);
            }
            if (doStats) {
                float rm = fmaxf(vj[0], vj[1]);
                rm = fmaxf(rm, __shfl_xor(rm, 1));
                rm = fmaxf(rm, __shfl_xor(rm, 2));
                rm = fmaxf(rm, __shfl_xor(rm, 4));
                rm = fmaxf(rm, __shfl_xor(rm, 8));
                float rs = __expf(vj[0] - rm) + __expf(vj[1] - rm);
                rs += __shfl_xor(rs, 1);
                rs += __shfl_xor(rs, 2);
                rs += __shfl_xor(rs, 4);
                rs += __shfl_xor(rs, 8);
                if (fr == 0) rowLDS[(wso + mf * 16 + fq * 4 + i) * 4 + (w & 3)] = make_float2(rm, rs);
            }
        }
    }
    if (doStats) {
        #pragma unroll
        for (int nf = 0; nf < 2; ++nf) {
            cmax[nf] = fmaxf(cmax[nf], __shfl_xor(cmax[nf], 16));
            cmax[nf] = fmaxf(cmax[nf], __shfl_xor(cmax[nf], 32));
        }
        float csum[2] = {0.f, 0.f};
        #pragma unroll
        for (int mf = 0; mf < 4; ++mf)
            #pragma unroll
            for (int i = 0; i < 4; ++i)
                #pragma unroll
                for (int nf = 0; nf < 2; ++nf) {
                    float v = acc[mf][nf][i] * (smv[mf][i] * (float)imv[nf]);
                    v = (v != 0.0f) ? v : NEGV;
                    csum[nf] += __expf(v - cmax[nf]);
                }
        #pragma unroll
        for (int nf = 0; nf < 2; ++nf) {
            csum[nf] += __shfl_xor(csum[nf], 16);
            csum[nf] += __shfl_xor(csum[nf], 32);
        }
        if (lane < 16) {
            #pragma unroll
            for (int nf = 0; nf < 2; ++nf)
                colLDS[(wro + nf * 16 + lane) * 2 + (w >> 2)] = make_float2(cmax[nf], csum[nf]);
        }
        __syncthreads();
        if (tid < 128) {
            float2 q0 = rowLDS[tid * 4 + 0], q1 = rowLDS[tid * 4 + 1];
            float2 q2 = rowLDS[tid * 4 + 2], q3 = rowLDS[tid * 4 + 3];
            const float m = fmaxf(fmaxf(q0.x, q1.x), fmaxf(q2.x, q3.x));
            const float ssum = q0.y * __expf(q0.x - m) + q1.y * __expf(q1.x - m)
                             + q2.y * __expf(q2.x - m) + q3.y * __expf(q3.x - m);
            rowP[((size_t)b * NS + s0 + tid) * 2 + blockIdx.x] = make_float2(m, ssum);
        } else if (tid < 256) {
            const int c = tid - 128;
            const float2 q0 = colLDS[c * 2 + 0], q1 = colLDS[c * 2 + 1];
            const float m = fmaxf(q0.x, q1.x);
            const float ssum = q0.y * __expf(q0.x - m) + q1.y * __expf(q1.x - m);
            colP[((size_t)b * NR + r0 + c) * 4 + blockIdx.y] = make_float2(m, ssum);
        }
    }
}

// ================================================================ combine partials -> m1,f1 (rows), m2,f2 (cols)   [r4-verbatim]
__global__ __launch_bounds__(256) void combine_stats(
    const float2* __restrict__ rowP, const float2* __restrict__ colP,
    const int* __restrict__ smask, const int* __restrict__ imask,
    float* __restrict__ m1, float* __restrict__ f1,
    float* __restrict__ m2, float* __restrict__ f2) {
    const int idx = blockIdx.x * 256 + threadIdx.x;
    if (idx < B_ * NS) {
        const float2 p0 = rowP[(size_t)idx * 2 + 0];
        const float2 p1 = rowP[(size_t)idx * 2 + 1];
        const float m = fmaxf(p0.x, p1.x);
        const float s = p0.y * __expf(p0.x - m) + p1.y * __expf(p1.x - m);
        m1[idx] = m;
        f1[idx] = (float)smask[idx] / s;
    } else if (idx < B_ * NS + B_ * NR) {
        const int j = idx - B_ * NS;
        const float2 p0 = colP[(size_t)j * 4 + 0];
        const float2 p1 = colP[(size_t)j * 4 + 1];
        const float2 p2 = colP[(size_t)j * 4 + 2];
        const float2 p3 = colP[(size_t)j * 4 + 3];
        const float m = fmaxf(fmaxf(p0.x, p1.x), fmaxf(p2.x, p3.x));
        const float s = p0.y * __expf(p0.x - m) + p1.y * __expf(p1.x - m)
                      + p2.y * __expf(p2.x - m) + p3.y * __expf(p3.x - m);
        m2[j] = m;
        f2[j] = (float)imask[j] / s;
    }
}

// ================================================================ transpose f32 -> bf16, K-swizzled within 64-chunks by (d&7)<<3  [r4-verbatim]
__global__ __launch_bounds__(256) void transpose_swz(
    const float* __restrict__ src, unsigned short* __restrict__ dst, int N) {
    const int b = blockIdx.z, n0 = blockIdx.y * 32, d0 = blockIdx.x * 32;
    __shared__ unsigned short T[32][36];
    const int t = threadIdx.x;
    {
        const int n = t >> 3, dq = (t & 7) * 4;
        const float4 v = *reinterpret_cast<const float4*>(src + ((size_t)b * N + n0 + n) * DD + d0 + dq);
        T[dq + 0][n] = f2bf(v.x); T[dq + 1][n] = f2bf(v.y);
        T[dq + 2][n] = f2bf(v.z); T[dq + 3][n] = f2bf(v.w);
    }
    __syncthreads();
    {
        const int d = t >> 3, nq = (t & 7) * 4;
        const int dg = d0 + d;
        const int base = n0 + nq;
        const int pos = (base & 63) ^ ((dg & 7) << 3);
        const size_t idx = ((size_t)b * DD + dg) * N + (base & ~63) + pos;
        *reinterpret_cast<ushort4*>(dst + idx) = *reinterpret_cast<const ushort4*>(&T[d][nq]);
    }
}

// ================================================================ build w1 ([s][r], swizzled) AND w2 ([r][s], swizzled) in one att pass  [r4-verbatim]
__global__ __launch_bounds__(256) void build_w12(
    const float* __restrict__ att, const int* __restrict__ smask,
    const int* __restrict__ imask,
    const float* __restrict__ m1, const float* __restrict__ f1,
    const float* __restrict__ m2, const float* __restrict__ f2,
    unsigned short* __restrict__ w1g, unsigned short* __restrict__ w2g) {
    const int b = blockIdx.z, s0 = blockIdx.y * 64, r0 = blockIdx.x * 64;
    __shared__ unsigned short T[64][68];
    __shared__ float m2s[64], f2s[64], ims[64];
    const int tid = threadIdx.x;
    if (tid < 64) {
        m2s[tid] = m2[b * NR + r0 + tid];
        f2s[tid] = f2[b * NR + r0 + tid];
        ims[tid] = (float)imask[b * NR + r0 + tid];
    }
    __syncthreads();
    {
        const int srow = tid >> 2, rg = (tid & 3) * 16;
        const int s = s0 + srow;
        const float m1v = m1[b * NS + s], f1v = f1[b * NS + s];
        const float smv = (float)smask[b * NS + s];
        const float* arow = att + ((size_t)b * NS + s) * NR + r0;
        const int w1swz = (s & 7) << 3;
        unsigned short* w1row = w1g + ((size_t)b * NS + s) * NR + r0;
        #pragma unroll
        for (int g = 0; g < 4; ++g) {
            const int rr = rg + g * 4;
            const float4 a = *reinterpret_cast<const float4*>(arow + rr);
            const float e0 = __expf(a.x - m1v) * f1v * ims[rr + 0];
            const float e1 = __expf(a.y - m1v) * f1v * ims[rr + 1];
            const float e2 = __expf(a.z - m1v) * f1v * ims[rr + 2];
            const float e3 = __expf(a.w - m1v) * f1v * ims[rr + 3];
            uint2 u; u.x = pk2(e0, e1); u.y = pk2(e2, e3);
            *reinterpret_cast<uint2*>(w1row + (rr ^ w1swz)) = u;
            const float q0 = __expf(a.x - m2s[rr + 0]) * f2s[rr + 0] * smv;
            const float q1 = __expf(a.y - m2s[rr + 1]) * f2s[rr + 1] * smv;
            const float q2 = __expf(a.z - m2s[rr + 2]) * f2s[rr + 2] * smv;
            const float q3 = __expf(a.w - m2s[rr + 3]) * f2s[rr + 3] * smv;
            const unsigned t0 = pk2(q0, q1), t1 = pk2(q2, q3);
            T[rr + 0][srow] = (unsigned short)(t0 & 0xFFFF);
            T[rr + 1][srow] = (unsigned short)(t0 >> 16);
            T[rr + 2][srow] = (unsigned short)(t1 & 0xFFFF);
            T[rr + 3][srow] = (unsigned short)(t1 >> 16);
        }
    }
    __syncthreads();
    {
        const int rl = tid >> 2, sg = (tid & 3) * 16;
        const int w2swz = (rl & 7) << 3;
        unsigned short* w2row = w2g + ((size_t)b * NR + r0 + rl) * NS + s0;
        #pragma unroll
        for (int g = 0; g < 4; ++g) {
            const int ss = sg + g * 4;
            *reinterpret_cast<ushort4*>(w2row + (ss ^ w2swz)) =
                *reinterpret_cast<const ushort4*>(&T[rl][ss]);
        }
    }
}

// ================================================================ apply GEMM [r4-verbatim]: C[64 m x 256 d] = A[m][K] @ Bt[d][K]
template<int KTOT, int MT, bool WOUT, int WIDX>
__global__ __launch_bounds__(256) void gemm_apply(
    const unsigned short* __restrict__ Ag, const unsigned short* __restrict__ Btg,
    const float* __restrict__ ref, float* __restrict__ outp, double* __restrict__ wsum) {
    const int b = blockIdx.z, m0 = blockIdx.y * 64, d0 = blockIdx.x * 256;
    __shared__ unsigned short As[64 * 64];
    __shared__ unsigned short Bs[256 * 64];
    __shared__ float redsum[256];
    const int tid = threadIdx.x, lane = tid & 63, w = tid >> 6;
    const int fr = lane & 15, fq = lane >> 4;
    f32x4 acc[4][4];
    #pragma unroll
    for (int i = 0; i < 4; ++i)
        #pragma unroll
        for (int j = 0; j < 4; ++j) acc[i][j] = (f32x4){0.f, 0.f, 0.f, 0.f};

    const int srow = tid >> 3;             // 0..31 staging row
    const int scol = (tid & 7) * 16;       // byte offset in 128B chunk
    for (int kc = 0; kc < KTOT / 64; ++kc) {
        const char* asrc = (const char*)(Ag + ((size_t)b * MT + m0) * KTOT) + kc * 128 + scol;
        #pragma unroll
        for (int c = 0; c < 2; ++c)
            gload16(asrc + (size_t)(c * 32 + srow) * (KTOT * 2), (char*)As + (c * 256 + tid) * 16);
        const char* bsrc = (const char*)(Btg + ((size_t)b * DD + d0) * KTOT) + kc * 128 + scol;
        #pragma unroll
        for (int c = 0; c < 8; ++c)
            gload16(bsrc + (size_t)(c * 32 + srow) * (KTOT * 2), (char*)Bs + (c * 256 + tid) * 16);
        __syncthreads();
        #pragma unroll
        for (int ks = 0; ks < 2; ++ks) {
            bf16x8 aF[4], bF[4];
            #pragma unroll
            for (int mf = 0; mf < 4; ++mf) {
                const int row = mf * 16 + fr;
                const int pos = (ks * 32 + fq * 8) ^ ((row & 7) << 3);
                aF[mf] = *reinterpret_cast<const bf16x8*>(&As[row * 64 + pos]);
            }
            #pragma unroll
            for (int nf = 0; nf < 4; ++nf) {
                const int row = w * 64 + nf * 16 + fr;
                const int pos = (ks * 32 + fq * 8) ^ ((row & 7) << 3);
                bF[nf] = *reinterpret_cast<const bf16x8*>(&Bs[row * 64 + pos]);
            }
            #pragma unroll
            for (int mf = 0; mf < 4; ++mf)
                #pragma unroll
                for (int nf = 0; nf < 4; ++nf)
                    acc[mf][nf] = __builtin_amdgcn_mfma_f32_16x16x32_bf16(aF[mf], bF[nf], acc[mf][nf], 0, 0, 0);
        }
        __syncthreads();
    }
    float sumsq = 0.0f;
    #pragma unroll
    for (int mf = 0; mf < 4; ++mf) {
        #pragma unroll
        for (int i = 0; i < 4; ++i) {
            const int row = m0 + mf * 16 + fq * 4 + i;
            const size_t base = ((size_t)b * MT + row) * DD + d0 + w * 64;
            #pragma unroll
            for (int nf = 0; nf < 4; ++nf) {
                const float v = acc[mf][nf][i];
                const float rv = ref[base + nf * 16 + fr];
                if constexpr (WOUT) outp[base + nf * 16 + fr] = v;
                const float dx = rv - v;
                sumsq += dx * dx;
            }
        }
    }
    redsum[tid] = sumsq; __syncthreads();
    for (int off = 128; off; off >>= 1) {
        if (tid < off) redsum[tid] += redsum[tid + off];
        __syncthreads();
    }
    if (tid == 0) atomicAdd(wsum + WIDX, (double)redsum[0]);
}

// ================================================================ fallback f32 kernels (used when ws too small)
__global__ __launch_bounds__(256) void first_kernel(
    const float* __restrict__ span, const float* __restrict__ image,
    const int* __restrict__ smask, const int* __restrict__ imask,
    const float* __restrict__ att, float* __restrict__ att_first,
    double* __restrict__ ws) {
    const int b  = blockIdx.y;
    const int s0 = blockIdx.x * 32;
    __shared__ float wT[256][36];
    __shared__ float Is[32][132];
    __shared__ float red[256];
    const int tid  = threadIdx.x;
    const int lane = tid & 63, wave = tid >> 6;
    for (int i = 0; i < 8; ++i) {
        const int srel = wave * 8 + i;
        const int s    = s0 + srel;
        const float4 v = *reinterpret_cast<const float4*>(att + ((size_t)b * NS + s) * NR + lane * 4);
        float m = fmaxf(fmaxf(v.x, v.y), fmaxf(v.z, v.w));
        #pragma unroll
        for (int off = 32; off; off >>= 1) m = fmaxf(m, __shfl_xor(m, off));
        float4 e;
        e.x = expf(v.x - m); e.y = expf(v.y - m); e.z = expf(v.z - m); e.w = expf(v.w - m);
        float sum = e.x + e.y + e.z + e.w;
        #pragma unroll
        for (int off = 32; off; off >>= 1) sum += __shfl_xor(sum, off);
        const float fac = (float)smask[b * NS + s] / sum;
        const int4 im4 = *reinterpret_cast<const int4*>(imask + b * NR + lane * 4);
        wT[lane * 4 + 0][srel] = e.x * fac * (float)im4.x;
        wT[lane * 4 + 1][srel] = e.y * fac * (float)im4.y;
        wT[lane * 4 + 2][srel] = e.z * fac * (float)im4.z;
        wT[lane * 4 + 3][srel] = e.w * fac * (float)im4.w;
    }
    __syncthreads();
    float sumsq = 0.0f;
    const int txd = tid & 31;
    const int tys = tid >> 5;
    const float* Ib = image + (size_t)b * NR * DD;
    for (int dc = 0; dc < 8; ++dc) {
        const int d0 = dc * 128;
        float acc[4][4] = {};
        for (int rc = 0; rc < 8; ++rc) {
            const int r0 = rc * 32;
            {
                const int rr = tid >> 3;
                const int cb = tid & 7;
                const float* src = Ib + (size_t)(r0 + rr) * DD + d0;
                #pragma unroll
                for (int q = 0; q < 4; ++q)
                    *reinterpret_cast<float4*>(&Is[rr][(cb + 8 * q) * 4]) =
                        *reinterpret_cast<const float4*>(src + (cb + 8 * q) * 4);
            }
            __syncthreads();
            #pragma unroll 4
            for (int rr = 0; rr < 32; ++rr) {
                const float4 wv = *reinterpret_cast<const float4*>(&wT[r0 + rr][tys * 4]);
                const float4 iv = *reinterpret_cast<const float4*>(&Is[rr][txd * 4]);
                const float wvv[4] = {wv.x, wv.y, wv.z, wv.w};
                const float ivv[4] = {iv.x, iv.y, iv.z, iv.w};
                #pragma unroll
                for (int i = 0; i < 4; ++i)
                    #pragma unroll
                    for (int j = 0; j < 4; ++j)
                        acc[i][j] += wvv[i] * ivv[j];
            }
            __syncthreads();
        }
        #pragma unroll
        for (int i = 0; i < 4; ++i) {
            const int s = s0 + tys * 4 + i;
            const size_t base = ((size_t)b * NS + s) * DD + d0 + txd * 4;
            const float4 af = {acc[i][0], acc[i][1], acc[i][2], acc[i][3]};
            *reinterpret_cast<float4*>(att_first + base) = af;
            const float4 sp = *reinterpret_cast<const float4*>(span + base);
            float dx;
            dx = sp.x - af.x; sumsq += dx * dx;
            dx = sp.y - af.y; sumsq += dx * dx;
            dx = sp.z - af.z; sumsq += dx * dx;
            dx = sp.w - af.w; sumsq += dx * dx;
        }
    }
    red[tid] = sumsq; __syncthreads();
    for (int off = 128; off; off >>= 1) {
        if (tid < off) red[tid] += red[tid + off];
        __syncthreads();
    }
    if (tid == 0) atomicAdd(ws, (double)red[0]);
}

__global__ __launch_bounds__(256) void second_kernel(
    const float* __restrict__ span, const float* __restrict__ image,
    const int* __restrict__ smask, const int* __restrict__ imask,
    const float* __restrict__ att, double* __restrict__ ws) {
    const int b  = blockIdx.y;
    const int r0 = blockIdx.x * 32;
    __shared__ float w2s[32][36];
    __shared__ float Ss[32][132];
    __shared__ float mArr[32], fArr[32];
    __shared__ float redm[8][32];
    __shared__ float red[256];
    const int tid = threadIdx.x;
    const int rr = tid & 31, q = tid >> 5;
    const float* attb = att + (size_t)b * NS * NR + r0 + rr;
    float mloc = -3.4e38f;
    for (int t = 0; t < 64; ++t)
        mloc = fmaxf(mloc, attb[(size_t)(q * 64 + t) * NR]);
    redm[q][rr] = mloc;
    __syncthreads();
    if (tid < 32) {
        float m = redm[0][tid];
        #pragma unroll
        for (int qq = 1; qq < 8; ++qq) m = fmaxf(m, redm[qq][tid]);
        mArr[tid] = m;
    }
    __syncthreads();
    const float mcol = mArr[rr];
    float sloc = 0.0f;
    for (int t = 0; t < 64; ++t)
        sloc += expf(attb[(size_t)(q * 64 + t) * NR] - mcol);
    redm[q][rr] = sloc;
    __syncthreads();
    if (tid < 32) {
        float s = 0.0f;
        #pragma unroll
        for (int qq = 0; qq < 8; ++qq) s += redm[qq][tid];
        fArr[tid] = (float)imask[b * NR + r0 + tid] / s;
    }
    __syncthreads();
    float sumsq = 0.0f;
    const int txd = tid & 31;
    const int tyr = tid >> 5;
    const float* Sb = span + (size_t)b * NS * DD;
    for (int dc = 0; dc < 8; ++dc) {
        const int d0 = dc * 128;
        float acc[4][4] = {};
        for (int sc = 0; sc < 16; ++sc) {
            const int sb0 = sc * 32;
            {
                const int sr = tid >> 3;
                const int cb = tid & 7;
                const float* src = Sb + (size_t)(sb0 + sr) * DD + d0;
                #pragma unroll
                for (int qq = 0; qq < 4; ++qq)
                    *reinterpret_cast<float4*>(&Ss[sr][(cb + 8 * qq) * 4]) =
                        *reinterpret_cast<const float4*>(src + (cb + 8 * qq) * 4);
            }
            {
                const int ss = tid >> 3;
                const int rq = (tid & 7) * 4;
                const int s  = sb0 + ss;
                const float4 v = *reinterpret_cast<const float4*>(att + ((size_t)b * NS + s) * NR + r0 + rq);
                const float smv = (float)smask[b * NS + s];
                float4 wv;
                wv.x = expf(v.x - mArr[rq + 0]) * fArr[rq + 0] * smv;
                wv.y = expf(v.y - mArr[rq + 1]) * fArr[rq + 1] * smv;
                wv.z = expf(v.z - mArr[rq + 2]) * fArr[rq + 2] * smv;
                wv.w = expf(v.w - mArr[rq + 3]) * fArr[rq + 3] * smv;
                *reinterpret_cast<float4*>(&w2s[ss][rq]) = wv;
            }
            __syncthreads();
            #pragma unroll 4
            for (int ss = 0; ss < 32; ++ss) {
                const float4 wv = *reinterpret_cast<const float4*>(&w2s[ss][tyr * 4]);
                const float4 sv = *reinterpret_cast<const float4*>(&Ss[ss][txd * 4]);
                const float wvv[4] = {wv.x, wv.y, wv.z, wv.w};
                const float svv[4] = {sv.x, sv.y, sv.z, sv.w};
                #pragma unroll
                for (int i = 0; i < 4; ++i)
                    #pragma unroll
                    for (int j = 0; j < 4; ++j)
                        acc[i][j] += wvv[i] * svv[j];
            }
            __syncthreads();
        }
        #pragma unroll
        for (int i = 0; i < 4; ++i) {
            const int r = r0 + tyr * 4 + i;
            const float4 iv = *reinterpret_cast<const float4*>(image + ((size_t)b * NR + r) * DD + d0 + txd * 4);
            float dx;
            dx = iv.x - acc[i][0]; sumsq += dx * dx;
            dx = iv.y - acc[i][1]; sumsq += dx * dx;
            dx = iv.z - acc[i][2]; sumsq += dx * dx;
            dx = iv.w - acc[i][3]; sumsq += dx * dx;
        }
    }
    red[tid] = sumsq; __syncthreads();
    for (int off = 128; off; off >>= 1) {
        if (tid < off) red[tid] += red[tid + off];
        __syncthreads();
    }
    if (tid == 0) atomicAdd(ws + 1, (double)red[0]);
}

// ---------------------------------------------------------------- final score
__global__ __launch_bounds__(64) void score_kernel(const double* __restrict__ ws, float* __restrict__ out) {
    if (threadIdx.x == 0) {
        out[0] = (float)(ws[0] / (double)((size_t)B_ * NS * DD) +
                         ws[1] / (double)((size_t)B_ * NR * DD));
    }
}

extern "C" void kernel_launch(void* const* d_in, const int* in_sizes, int n_in,
                              void* d_out, int out_size, void* d_ws, size_t ws_size,
                              hipStream_t stream) {
    const float* span  = (const float*)d_in[0];
    const float* image = (const float*)d_in[1];
    const int*   smask = (const int*)d_in[2];
    const int*   imask = (const int*)d_in[3];
    float* out       = (float*)d_out;
    float* att_first = out + 1;
    float* att       = out + 1 + (size_t)B_ * NS * DD;

    // ws layout (r4):
    //  wsum(512B) | m1,f1 (B*NS f32 each) | m2,f2 (B*NR f32 each)
    //  | rowP (B*NS*2 float2) | colP (B*NR*4 float2)
    //  | X0: phase1 = { imgT (33.5M), w1 (16.8M) }
    //        phase2 = { spT [0,67.1M) } (overwrites imgT+w1 after gemm1)
    //        w2 at [67.1M, 83.9M)       (live from build_w12 to gemm2)
    char* base = (char*)d_ws;
    double* wsum = (double*)base;
    float* m1 = (float*)(base + 512);
    float* f1 = m1 + (size_t)B_ * NS;
    float* m2 = f1 + (size_t)B_ * NS;
    float* f2 = m2 + (size_t)B_ * NR;
    float2* rowP = (float2*)(f2 + (size_t)B_ * NR);
    float2* colP = rowP + (size_t)B_ * NS * 2;
    char* X0 = (char*)(colP + (size_t)B_ * NR * 4);
    unsigned short* imgT = (unsigned short*)X0;
    unsigned short* w1g  = (unsigned short*)(X0 + (size_t)B_ * DD * NR * 2);
    unsigned short* spT  = (unsigned short*)X0;
    unsigned short* w2g  = (unsigned short*)(X0 + (size_t)B_ * DD * NS * 2);
    const size_t NEED = (size_t)(X0 - base) + (size_t)B_ * DD * NS * 2 + (size_t)B_ * NS * NR * 2;
    const int wsok = (ws_size >= NEED) ? 1 : 0;

    zero_ws<<<dim3(1), dim3(64), 0, stream>>>(wsum);
    att_mfma<<<dim3(NR / 128, NS / 128, B_), dim3(512), 0, stream>>>(
        span, image, smask, imask, att, rowP, colP, wsok);

    if (wsok) {
        combine_stats<<<dim3((B_ * NS + B_ * NR) / 256), dim3(256), 0, stream>>>(
            rowP, colP, smask, imask, m1, f1, m2, f2);
        transpose_swz<<<dim3(DD / 32, NR / 32, B_), dim3(256), 0, stream>>>(image, imgT, NR);
        build_w12<<<dim3(NR / 64, NS / 64, B_), dim3(256), 0, stream>>>(
            att, smask, imask, m1, f1, m2, f2, w1g, w2g);
        gemm_apply<NR, NS, true, 0><<<dim3(DD / 256, NS / 64, B_), dim3(256), 0, stream>>>(
            w1g, imgT, span, att_first, wsum);
        transpose_swz<<<dim3(DD / 32, NS / 32, B_), dim3(256), 0, stream>>>(span, spT, NS);
        gemm_apply<NS, NR, false, 1><<<dim3(DD / 256, NR / 64, B_), dim3(256), 0, stream>>>(
            w2g, spT, image, nullptr, wsum);
    } else {
        first_kernel<<<dim3(NS / 32, B_), dim3(256), 0, stream>>>(span, image, smask, imask, att, att_first, wsum);
        second_kernel<<<dim3(NR / 32, B_), dim3(256), 0, stream>>>(span, image, smask, imask, att, wsum);
    }
    score_kernel<<<dim3(1), dim3(64), 0, stream>>>(wsum, out);
}

// Round 11
// 317.066 us; speedup vs baseline: 1.0648x; 1.0047x over previous
//
#include <hip/hip_runtime.h>
#include <hip/hip_bf16.h>
#include <math.h>

#define B_  64
#define NS  512
#define NR  256
#define DD  1024
#define NEGV (-1e10f)

typedef __attribute__((ext_vector_type(4))) float f32x4;
typedef __attribute__((ext_vector_type(8))) short bf16x8;

__device__ __forceinline__ unsigned short f2bf(float x) {
    unsigned u = __builtin_bit_cast(unsigned, x);
    unsigned r = u + 0x7FFFu + ((u >> 16) & 1u);
    return (unsigned short)(r >> 16);
}
// packed bf16 convert: D.lo = bf16(x), D.hi = bf16(y)
__device__ __forceinline__ unsigned pk2(float x, float y) {
    unsigned r;
    asm("v_cvt_pk_bf16_f32 %0, %1, %2" : "=v"(r) : "v"(x), "v"(y));
    return r;
}
// async global->LDS, 16B per lane
__device__ __forceinline__ void gload16(const void* g, void* l) {
    __builtin_amdgcn_global_load_lds((const __attribute__((address_space(1))) void*)g,
                                     (__attribute__((address_space(3))) void*)l, 16, 0, 0);
}

// ---------------------------------------------------------------- zero ws
__global__ __launch_bounds__(64) void zero_ws(double* ws) {
    if (threadIdx.x == 0) { ws[0] = 0.0; ws[1] = 0.0; }
}

// ================================================================ stage 1
// att = masked span @ image^T, SINGLE-PASS bf16 MFMA, 128x128 tile,
// 512 threads / 8 waves (wave = 64s x 32r). r3/r10 loop schedule.
// Full exp softmax partial stats in epilogue (feeds combine_stats).
__global__ __launch_bounds__(512) void att_mfma(
    const float* __restrict__ span, const float* __restrict__ image,
    const int* __restrict__ smask, const int* __restrict__ imask,
    float* __restrict__ att, float2* __restrict__ rowP, float2* __restrict__ colP,
    int doStats) {
    const int b  = blockIdx.z;
    const int s0 = blockIdx.y * 128;
    const int r0 = blockIdx.x * 128;
    __shared__ unsigned short Abuf[128][40], Bbuf[128][40];   // 20KB
    const int tid  = threadIdx.x;
    const int lane = tid & 63;
    const int w    = tid >> 6;        // 0..7
    const int wso  = (w >> 2) * 64;   // s-half
    const int wro  = (w & 3) * 32;    // r-quarter
    const float* Sp = span  + ((size_t)b * NS + s0) * DD;
    const float* Im = image + ((size_t)b * NR + r0) * DD;

    f32x4 acc[4][2];
    #pragma unroll
    for (int i = 0; i < 4; ++i)
        #pragma unroll
        for (int j = 0; j < 2; ++j) acc[i][j] = (f32x4){0.f, 0.f, 0.f, 0.f};

    const int row0 = tid >> 2;        // 0..127 (one row per thread)
    const int kq   = (tid & 3) * 8;   // 0,8,16,24
    const int fr   = lane & 15;
    const int fq   = lane >> 4;
    const int fk   = fq * 8;

    for (int k0 = 0; k0 < DD; k0 += 32) {
        {
            const float4 a0 = *reinterpret_cast<const float4*>(Sp + (size_t)row0 * DD + k0 + kq);
            const float4 a1 = *reinterpret_cast<const float4*>(Sp + (size_t)row0 * DD + k0 + kq + 4);
            const float4 c0 = *reinterpret_cast<const float4*>(Im + (size_t)row0 * DD + k0 + kq);
            const float4 c1 = *reinterpret_cast<const float4*>(Im + (size_t)row0 * DD + k0 + kq + 4);
            uint4 u;
            u.x = pk2(a0.x, a0.y); u.y = pk2(a0.z, a0.w);
            u.z = pk2(a1.x, a1.y); u.w = pk2(a1.z, a1.w);
            *reinterpret_cast<uint4*>(&Abuf[row0][kq]) = u;
            u.x = pk2(c0.x, c0.y); u.y = pk2(c0.z, c0.w);
            u.z = pk2(c1.x, c1.y); u.w = pk2(c1.z, c1.w);
            *reinterpret_cast<uint4*>(&Bbuf[row0][kq]) = u;
        }
        __syncthreads();
        bf16x8 ah[4], bh[2];
        #pragma unroll
        for (int mf = 0; mf < 4; ++mf)
            ah[mf] = *reinterpret_cast<const bf16x8*>(&Abuf[wso + mf * 16 + fr][fk]);
        #pragma unroll
        for (int nf = 0; nf < 2; ++nf)
            bh[nf] = *reinterpret_cast<const bf16x8*>(&Bbuf[wro + nf * 16 + fr][fk]);
        #pragma unroll
        for (int mf = 0; mf < 4; ++mf)
            #pragma unroll
            for (int nf = 0; nf < 2; ++nf)
                acc[mf][nf] = __builtin_amdgcn_mfma_f32_16x16x32_bf16(ah[mf], bh[nf], acc[mf][nf], 0, 0, 0);
        __syncthreads();
    }

    // ---- epilogue: mask + zero->NEG store + fused exp softmax partial stats
    float2* rowLDS = reinterpret_cast<float2*>(&Abuf[0][0]);   // [128][4]
    float2* colLDS = rowLDS + 512;                             // [128][2]
    int imv[2];
    #pragma unroll
    for (int nf = 0; nf < 2; ++nf) imv[nf] = imask[b * NR + r0 + wro + nf * 16 + fr];
    float cmax[2] = {-3.4e38f, -3.4e38f};
    float smv[4][4];
    #pragma unroll
    for (int mf = 0; mf < 4; ++mf) {
        #pragma unroll
        for (int i = 0; i < 4; ++i) {
            const int s = s0 + wso + mf * 16 + fq * 4 + i;
            const int sm = smask[b * NS + s];
            smv[mf][i] = (float)sm;
            float* orow = att + ((size_t)b * NS + s) * NR + r0 + wro;
            float vj[2];
            #pragma unroll
            for (int nf = 0; nf < 2; ++nf) {
                float v = acc[mf][nf][i] * (float)(sm * imv[nf]);
                v = (v != 0.0f) ? v : NEGV;
                orow[nf * 16 + fr] = v;
                vj[nf] = v;
                cmax[nf] = fmaxf(cmax[nf], v);
            }
            if (doStats) {
                float rm = fmaxf(vj[0], vj[1]);
                rm = fmaxf(rm, __shfl_xor(rm, 1));
                rm = fmaxf(rm, __shfl_xor(rm, 2));
                rm = fmaxf(rm, __shfl_xor(rm, 4));
                rm = fmaxf(rm, __shfl_xor(rm, 8));
                float rs = __expf(vj[0] - rm) + __expf(vj[1] - rm);
                rs += __shfl_xor(rs, 1);
                rs += __shfl_xor(rs, 2);
                rs += __shfl_xor(rs, 4);
                rs += __shfl_xor(rs, 8);
                if (fr == 0) rowLDS[(wso + mf * 16 + fq * 4 + i) * 4 + (w & 3)] = make_float2(rm, rs);
            }
        }
    }
    if (doStats) {
        #pragma unroll
        for (int nf = 0; nf < 2; ++nf) {
            cmax[nf] = fmaxf(cmax[nf], __shfl_xor(cmax[nf], 16));
            cmax[nf] = fmaxf(cmax[nf], __shfl_xor(cmax[nf], 32));
        }
        float csum[2] = {0.f, 0.f};
        #pragma unroll
        for (int mf = 0; mf < 4; ++mf)
            #pragma unroll
            for (int i = 0; i < 4; ++i)
                #pragma unroll
                for (int nf = 0; nf < 2; ++nf) {
                    float v = acc[mf][nf][i] * (smv[mf][i] * (float)imv[nf]);
                    v = (v != 0.0f) ? v : NEGV;
                    csum[nf] += __expf(v - cmax[nf]);
                }
        #pragma unroll
        for (int nf = 0; nf < 2; ++nf) {
            csum[nf] += __shfl_xor(csum[nf], 16);
            csum[nf] += __shfl_xor(csum[nf], 32);
        }
        if (lane < 16) {
            #pragma unroll
            for (int nf = 0; nf < 2; ++nf)
                colLDS[(wro + nf * 16 + lane) * 2 + (w >> 2)] = make_float2(cmax[nf], csum[nf]);
        }
        __syncthreads();
        if (tid < 128) {
            float2 q0 = rowLDS[tid * 4 + 0], q1 = rowLDS[tid * 4 + 1];
            float2 q2 = rowLDS[tid * 4 + 2], q3 = rowLDS[tid * 4 + 3];
            const float m = fmaxf(fmaxf(q0.x, q1.x), fmaxf(q2.x, q3.x));
            const float ssum = q0.y * __expf(q0.x - m) + q1.y * __expf(q1.x - m)
                             + q2.y * __expf(q2.x - m) + q3.y * __expf(q3.x - m);
            rowP[((size_t)b * NS + s0 + tid) * 2 + blockIdx.x] = make_float2(m, ssum);
        } else if (tid < 256) {
            const int c = tid - 128;
            const float2 q0 = colLDS[c * 2 + 0], q1 = colLDS[c * 2 + 1];
            const float m = fmaxf(q0.x, q1.x);
            const float ssum = q0.y * __expf(q0.x - m) + q1.y * __expf(q1.x - m);
            colP[((size_t)b * NR + r0 + c) * 4 + blockIdx.y] = make_float2(m, ssum);
        }
    }
}

// ================================================================ combine partials -> m1,f1 (rows), m2,f2 (cols)   [r4-verbatim]
__global__ __launch_bounds__(256) void combine_stats(
    const float2* __restrict__ rowP, const float2* __restrict__ colP,
    const int* __restrict__ smask, const int* __restrict__ imask,
    float* __restrict__ m1, float* __restrict__ f1,
    float* __restrict__ m2, float* __restrict__ f2) {
    const int idx = blockIdx.x * 256 + threadIdx.x;
    if (idx < B_ * NS) {
        const float2 p0 = rowP[(size_t)idx * 2 + 0];
        const float2 p1 = rowP[(size_t)idx * 2 + 1];
        const float m = fmaxf(p0.x, p1.x);
        const float s = p0.y * __expf(p0.x - m) + p1.y * __expf(p1.x - m);
        m1[idx] = m;
        f1[idx] = (float)smask[idx] / s;
    } else if (idx < B_ * NS + B_ * NR) {
        const int j = idx - B_ * NS;
        const float2 p0 = colP[(size_t)j * 4 + 0];
        const float2 p1 = colP[(size_t)j * 4 + 1];
        const float2 p2 = colP[(size_t)j * 4 + 2];
        const float2 p3 = colP[(size_t)j * 4 + 3];
        const float m = fmaxf(fmaxf(p0.x, p1.x), fmaxf(p2.x, p3.x));
        const float s = p0.y * __expf(p0.x - m) + p1.y * __expf(p1.x - m)
                      + p2.y * __expf(p2.x - m) + p3.y * __expf(p3.x - m);
        m2[j] = m;
        f2[j] = (float)imask[j] / s;
    }
}

// ================================================================ transpose f32 -> bf16, K-swizzled within 64-chunks by (d&7)<<3  [r4-verbatim]
__global__ __launch_bounds__(256) void transpose_swz(
    const float* __restrict__ src, unsigned short* __restrict__ dst, int N) {
    const int b = blockIdx.z, n0 = blockIdx.y * 32, d0 = blockIdx.x * 32;
    __shared__ unsigned short T[32][36];
    const int t = threadIdx.x;
    {
        const int n = t >> 3, dq = (t & 7) * 4;
        const float4 v = *reinterpret_cast<const float4*>(src + ((size_t)b * N + n0 + n) * DD + d0 + dq);
        T[dq + 0][n] = f2bf(v.x); T[dq + 1][n] = f2bf(v.y);
        T[dq + 2][n] = f2bf(v.z); T[dq + 3][n] = f2bf(v.w);
    }
    __syncthreads();
    {
        const int d = t >> 3, nq = (t & 7) * 4;
        const int dg = d0 + d;
        const int base = n0 + nq;
        const int pos = (base & 63) ^ ((dg & 7) << 3);
        const size_t idx = ((size_t)b * DD + dg) * N + (base & ~63) + pos;
        *reinterpret_cast<ushort4*>(dst + idx) = *reinterpret_cast<const ushort4*>(&T[d][nq]);
    }
}

// ================================================================ build w1 ([s][r], swizzled) AND w2 ([r][s], swizzled) in one att pass  [r4-verbatim]
__global__ __launch_bounds__(256) void build_w12(
    const float* __restrict__ att, const int* __restrict__ smask,
    const int* __restrict__ imask,
    const float* __restrict__ m1, const float* __restrict__ f1,
    const float* __restrict__ m2, const float* __restrict__ f2,
    unsigned short* __restrict__ w1g, unsigned short* __restrict__ w2g) {
    const int b = blockIdx.z, s0 = blockIdx.y * 64, r0 = blockIdx.x * 64;
    __shared__ unsigned short T[64][68];
    __shared__ float m2s[64], f2s[64], ims[64];
    const int tid = threadIdx.x;
    if (tid < 64) {
        m2s[tid] = m2[b * NR + r0 + tid];
        f2s[tid] = f2[b * NR + r0 + tid];
        ims[tid] = (float)imask[b * NR + r0 + tid];
    }
    __syncthreads();
    {
        const int srow = tid >> 2, rg = (tid & 3) * 16;
        const int s = s0 + srow;
        const float m1v = m1[b * NS + s], f1v = f1[b * NS + s];
        const float smv = (float)smask[b * NS + s];
        const float* arow = att + ((size_t)b * NS + s) * NR + r0;
        const int w1swz = (s & 7) << 3;
        unsigned short* w1row = w1g + ((size_t)b * NS + s) * NR + r0;
        #pragma unroll
        for (int g = 0; g < 4; ++g) {
            const int rr = rg + g * 4;
            const float4 a = *reinterpret_cast<const float4*>(arow + rr);
            const float e0 = __expf(a.x - m1v) * f1v * ims[rr + 0];
            const float e1 = __expf(a.y - m1v) * f1v * ims[rr + 1];
            const float e2 = __expf(a.z - m1v) * f1v * ims[rr + 2];
            const float e3 = __expf(a.w - m1v) * f1v * ims[rr + 3];
            uint2 u; u.x = pk2(e0, e1); u.y = pk2(e2, e3);
            *reinterpret_cast<uint2*>(w1row + (rr ^ w1swz)) = u;
            const float q0 = __expf(a.x - m2s[rr + 0]) * f2s[rr + 0] * smv;
            const float q1 = __expf(a.y - m2s[rr + 1]) * f2s[rr + 1] * smv;
            const float q2 = __expf(a.z - m2s[rr + 2]) * f2s[rr + 2] * smv;
            const float q3 = __expf(a.w - m2s[rr + 3]) * f2s[rr + 3] * smv;
            const unsigned t0 = pk2(q0, q1), t1 = pk2(q2, q3);
            T[rr + 0][srow] = (unsigned short)(t0 & 0xFFFF);
            T[rr + 1][srow] = (unsigned short)(t0 >> 16);
            T[rr + 2][srow] = (unsigned short)(t1 & 0xFFFF);
            T[rr + 3][srow] = (unsigned short)(t1 >> 16);
        }
    }
    __syncthreads();
    {
        const int rl = tid >> 2, sg = (tid & 3) * 16;
        const int w2swz = (rl & 7) << 3;
        unsigned short* w2row = w2g + ((size_t)b * NR + r0 + rl) * NS + s0;
        #pragma unroll
        for (int g = 0; g < 4; ++g) {
            const int ss = sg + g * 4;
            *reinterpret_cast<ushort4*>(w2row + (ss ^ w2swz)) =
                *reinterpret_cast<const ushort4*>(&T[rl][ss]);
        }
    }
}

// ================================================================ apply GEMM [r4-verbatim]: C[64 m x 256 d] = A[m][K] @ Bt[d][K]
template<int KTOT, int MT, bool WOUT, int WIDX>
__global__ __launch_bounds__(256) void gemm_apply(
    const unsigned short* __restrict__ Ag, const unsigned short* __restrict__ Btg,
    const float* __restrict__ ref, float* __restrict__ outp, double* __restrict__ wsum) {
    const int b = blockIdx.z, m0 = blockIdx.y * 64, d0 = blockIdx.x * 256;
    __shared__ unsigned short As[64 * 64];
    __shared__ unsigned short Bs[256 * 64];
    __shared__ float redsum[256];
    const int tid = threadIdx.x, lane = tid & 63, w = tid >> 6;
    const int fr = lane & 15, fq = lane >> 4;
    f32x4 acc[4][4];
    #pragma unroll
    for (int i = 0; i < 4; ++i)
        #pragma unroll
        for (int j = 0; j < 4; ++j) acc[i][j] = (f32x4){0.f, 0.f, 0.f, 0.f};

    const int srow = tid >> 3;             // 0..31 staging row
    const int scol = (tid & 7) * 16;       // byte offset in 128B chunk
    for (int kc = 0; kc < KTOT / 64; ++kc) {
        const char* asrc = (const char*)(Ag + ((size_t)b * MT + m0) * KTOT) + kc * 128 + scol;
        #pragma unroll
        for (int c = 0; c < 2; ++c)
            gload16(asrc + (size_t)(c * 32 + srow) * (KTOT * 2), (char*)As + (c * 256 + tid) * 16);
        const char* bsrc = (const char*)(Btg + ((size_t)b * DD + d0) * KTOT) + kc * 128 + scol;
        #pragma unroll
        for (int c = 0; c < 8; ++c)
            gload16(bsrc + (size_t)(c * 32 + srow) * (KTOT * 2), (char*)Bs + (c * 256 + tid) * 16);
        __syncthreads();
        #pragma unroll
        for (int ks = 0; ks < 2; ++ks) {
            bf16x8 aF[4], bF[4];
            #pragma unroll
            for (int mf = 0; mf < 4; ++mf) {
                const int row = mf * 16 + fr;
                const int pos = (ks * 32 + fq * 8) ^ ((row & 7) << 3);
                aF[mf] = *reinterpret_cast<const bf16x8*>(&As[row * 64 + pos]);
            }
            #pragma unroll
            for (int nf = 0; nf < 4; ++nf) {
                const int row = w * 64 + nf * 16 + fr;
                const int pos = (ks * 32 + fq * 8) ^ ((row & 7) << 3);
                bF[nf] = *reinterpret_cast<const bf16x8*>(&Bs[row * 64 + pos]);
            }
            #pragma unroll
            for (int mf = 0; mf < 4; ++mf)
                #pragma unroll
                for (int nf = 0; nf < 4; ++nf)
                    acc[mf][nf] = __builtin_amdgcn_mfma_f32_16x16x32_bf16(aF[mf], bF[nf], acc[mf][nf], 0, 0, 0);
        }
        __syncthreads();
    }
    float sumsq = 0.0f;
    #pragma unroll
    for (int mf = 0; mf < 4; ++mf) {
        #pragma unroll
        for (int i = 0; i < 4; ++i) {
            const int row = m0 + mf * 16 + fq * 4 + i;
            const size_t base = ((size_t)b * MT + row) * DD + d0 + w * 64;
            #pragma unroll
            for (int nf = 0; nf < 4; ++nf) {
                const float v = acc[mf][nf][i];
                const float rv = ref[base + nf * 16 + fr];
                if constexpr (WOUT) outp[base + nf * 16 + fr] = v;
                const float dx = rv - v;
                sumsq += dx * dx;
            }
        }
    }
    redsum[tid] = sumsq; __syncthreads();
    for (int off = 128; off; off >>= 1) {
        if (tid < off) redsum[tid] += redsum[tid + off];
        __syncthreads();
    }
    if (tid == 0) atomicAdd(wsum + WIDX, (double)redsum[0]);
}

// ================================================================ fallback f32 kernels (used when ws too small)
__global__ __launch_bounds__(256) void first_kernel(
    const float* __restrict__ span, const float* __restrict__ image,
    const int* __restrict__ smask, const int* __restrict__ imask,
    const float* __restrict__ att, float* __restrict__ att_first,
    double* __restrict__ ws) {
    const int b  = blockIdx.y;
    const int s0 = blockIdx.x * 32;
    __shared__ float wT[256][36];
    __shared__ float Is[32][132];
    __shared__ float red[256];
    const int tid  = threadIdx.x;
    const int lane = tid & 63, wave = tid >> 6;
    for (int i = 0; i < 8; ++i) {
        const int srel = wave * 8 + i;
        const int s    = s0 + srel;
        const float4 v = *reinterpret_cast<const float4*>(att + ((size_t)b * NS + s) * NR + lane * 4);
        float m = fmaxf(fmaxf(v.x, v.y), fmaxf(v.z, v.w));
        #pragma unroll
        for (int off = 32; off; off >>= 1) m = fmaxf(m, __shfl_xor(m, off));
        float4 e;
        e.x = expf(v.x - m); e.y = expf(v.y - m); e.z = expf(v.z - m); e.w = expf(v.w - m);
        float sum = e.x + e.y + e.z + e.w;
        #pragma unroll
        for (int off = 32; off; off >>= 1) sum += __shfl_xor(sum, off);
        const float fac = (float)smask[b * NS + s] / sum;
        const int4 im4 = *reinterpret_cast<const int4*>(imask + b * NR + lane * 4);
        wT[lane * 4 + 0][srel] = e.x * fac * (float)im4.x;
        wT[lane * 4 + 1][srel] = e.y * fac * (float)im4.y;
        wT[lane * 4 + 2][srel] = e.z * fac * (float)im4.z;
        wT[lane * 4 + 3][srel] = e.w * fac * (float)im4.w;
    }
    __syncthreads();
    float sumsq = 0.0f;
    const int txd = tid & 31;
    const int tys = tid >> 5;
    const float* Ib = image + (size_t)b * NR * DD;
    for (int dc = 0; dc < 8; ++dc) {
        const int d0 = dc * 128;
        float acc[4][4] = {};
        for (int rc = 0; rc < 8; ++rc) {
            const int r0 = rc * 32;
            {
                const int rr = tid >> 3;
                const int cb = tid & 7;
                const float* src = Ib + (size_t)(r0 + rr) * DD + d0;
                #pragma unroll
                for (int q = 0; q < 4; ++q)
                    *reinterpret_cast<float4*>(&Is[rr][(cb + 8 * q) * 4]) =
                        *reinterpret_cast<const float4*>(src + (cb + 8 * q) * 4);
            }
            __syncthreads();
            #pragma unroll 4
            for (int rr = 0; rr < 32; ++rr) {
                const float4 wv = *reinterpret_cast<const float4*>(&wT[r0 + rr][tys * 4]);
                const float4 iv = *reinterpret_cast<const float4*>(&Is[rr][txd * 4]);
                const float wvv[4] = {wv.x, wv.y, wv.z, wv.w};
                const float ivv[4] = {iv.x, iv.y, iv.z, iv.w};
                #pragma unroll
                for (int i = 0; i < 4; ++i)
                    #pragma unroll
                    for (int j = 0; j < 4; ++j)
                        acc[i][j] += wvv[i] * ivv[j];
            }
            __syncthreads();
        }
        #pragma unroll
        for (int i = 0; i < 4; ++i) {
            const int s = s0 + tys * 4 + i;
            const size_t base = ((size_t)b * NS + s) * DD + d0 + txd * 4;
            const float4 af = {acc[i][0], acc[i][1], acc[i][2], acc[i][3]};
            *reinterpret_cast<float4*>(att_first + base) = af;
            const float4 sp = *reinterpret_cast<const float4*>(span + base);
            float dx;
            dx = sp.x - af.x; sumsq += dx * dx;
            dx = sp.y - af.y; sumsq += dx * dx;
            dx = sp.z - af.z; sumsq += dx * dx;
            dx = sp.w - af.w; sumsq += dx * dx;
        }
    }
    red[tid] = sumsq; __syncthreads();
    for (int off = 128; off; off >>= 1) {
        if (tid < off) red[tid] += red[tid + off];
        __syncthreads();
    }
    if (tid == 0) atomicAdd(ws, (double)red[0]);
}

__global__ __launch_bounds__(256) void second_kernel(
    const float* __restrict__ span, const float* __restrict__ image,
    const int* __restrict__ smask, const int* __restrict__ imask,
    const float* __restrict__ att, double* __restrict__ ws) {
    const int b  = blockIdx.y;
    const int r0 = blockIdx.x * 32;
    __shared__ float w2s[32][36];
    __shared__ float Ss[32][132];
    __shared__ float mArr[32], fArr[32];
    __shared__ float redm[8][32];
    __shared__ float red[256];
    const int tid = threadIdx.x;
    const int rr = tid & 31, q = tid >> 5;
    const float* attb = att + (size_t)b * NS * NR + r0 + rr;
    float mloc = -3.4e38f;
    for (int t = 0; t < 64; ++t)
        mloc = fmaxf(mloc, attb[(size_t)(q * 64 + t) * NR]);
    redm[q][rr] = mloc;
    __syncthreads();
    if (tid < 32) {
        float m = redm[0][tid];
        #pragma unroll
        for (int qq = 1; qq < 8; ++qq) m = fmaxf(m, redm[qq][tid]);
        mArr[tid] = m;
    }
    __syncthreads();
    const float mcol = mArr[rr];
    float sloc = 0.0f;
    for (int t = 0; t < 64; ++t)
        sloc += expf(attb[(size_t)(q * 64 + t) * NR] - mcol);
    redm[q][rr] = sloc;
    __syncthreads();
    if (tid < 32) {
        float s = 0.0f;
        #pragma unroll
        for (int qq = 0; qq < 8; ++qq) s += redm[qq][tid];
        fArr[tid] = (float)imask[b * NR + r0 + tid] / s;
    }
    __syncthreads();
    float sumsq = 0.0f;
    const int txd = tid & 31;
    const int tyr = tid >> 5;
    const float* Sb = span + (size_t)b * NS * DD;
    for (int dc = 0; dc < 8; ++dc) {
        const int d0 = dc * 128;
        float acc[4][4] = {};
        for (int sc = 0; sc < 16; ++sc) {
            const int sb0 = sc * 32;
            {
                const int sr = tid >> 3;
                const int cb = tid & 7;
                const float* src = Sb + (size_t)(sb0 + sr) * DD + d0;
                #pragma unroll
                for (int qq = 0; qq < 4; ++qq)
                    *reinterpret_cast<float4*>(&Ss[sr][(cb + 8 * qq) * 4]) =
                        *reinterpret_cast<const float4*>(src + (cb + 8 * qq) * 4);
            }
            {
                const int ss = tid >> 3;
                const int rq = (tid & 7) * 4;
                const int s  = sb0 + ss;
                const float4 v = *reinterpret_cast<const float4*>(att + ((size_t)b * NS + s) * NR + r0 + rq);
                const float smv = (float)smask[b * NS + s];
                float4 wv;
                wv.x = expf(v.x - mArr[rq + 0]) * fArr[rq + 0] * smv;
                wv.y = expf(v.y - mArr[rq + 1]) * fArr[rq + 1] * smv;
                wv.z = expf(v.z - mArr[rq + 2]) * fArr[rq + 2] * smv;
                wv.w = expf(v.w - mArr[rq + 3]) * fArr[rq + 3] * smv;
                *reinterpret_cast<float4*>(&w2s[ss][rq]) = wv;
            }
            __syncthreads();
            #pragma unroll 4
            for (int ss = 0; ss < 32; ++ss) {
                const float4 wv = *reinterpret_cast<const float4*>(&w2s[ss][tyr * 4]);
                const float4 sv = *reinterpret_cast<const float4*>(&Ss[ss][txd * 4]);
                const float wvv[4] = {wv.x, wv.y, wv.z, wv.w};
                const float svv[4] = {sv.x, sv.y, sv.z, sv.w};
                #pragma unroll
                for (int i = 0; i < 4; ++i)
                    #pragma unroll
                    for (int j = 0; j < 4; ++j)
                        acc[i][j] += wvv[i] * svv[j];
            }
            __syncthreads();
        }
        #pragma unroll
        for (int i = 0; i < 4; ++i) {
            const int r = r0 + tyr * 4 + i;
            const float4 iv = *reinterpret_cast<const float4*>(image + ((size_t)b * NR + r) * DD + d0 + txd * 4);
            float dx;
            dx = iv.x - acc[i][0]; sumsq += dx * dx;
            dx = iv.y - acc[i][1]; sumsq += dx * dx;
            dx = iv.z - acc[i][2]; sumsq += dx * dx;
            dx = iv.w - acc[i][3]; sumsq += dx * dx;
        }
    }
    red[tid] = sumsq; __syncthreads();
    for (int off = 128; off; off >>= 1) {
        if (tid < off) red[tid] += red[tid + off];
        __syncthreads();
    }
    if (tid == 0) atomicAdd(ws + 1, (double)red[0]);
}

// ---------------------------------------------------------------- final score
__global__ __launch_bounds__(64) void score_kernel(const double* __restrict__ ws, float* __restrict__ out) {
    if (threadIdx.x == 0) {
        out[0] = (float)(ws[0] / (double)((size_t)B_ * NS * DD) +
                         ws[1] / (double)((size_t)B_ * NR * DD));
    }
}

extern "C" void kernel_launch(void* const* d_in, const int* in_sizes, int n_in,
                              void* d_out, int out_size, void* d_ws, size_t ws_size,
                              hipStream_t stream) {
    const float* span  = (const float*)d_in[0];
    const float* image = (const float*)d_in[1];
    const int*   smask = (const int*)d_in[2];
    const int*   imask = (const int*)d_in[3];
    float* out       = (float*)d_out;
    float* att_first = out + 1;
    float* att       = out + 1 + (size_t)B_ * NS * DD;

    // ws layout (r4):
    //  wsum(512B) | m1,f1 (B*NS f32 each) | m2,f2 (B*NR f32 each)
    //  | rowP (B*NS*2 float2) | colP (B*NR*4 float2)
    //  | X0: phase1 = { imgT (33.5M), w1 (16.8M) }
    //        phase2 = { spT [0,67.1M) } (overwrites imgT+w1 after gemm1)
    //        w2 at [67.1M, 83.9M)       (live from build_w12 to gemm2)
    char* base = (char*)d_ws;
    double* wsum = (double*)base;
    float* m1 = (float*)(base + 512);
    float* f1 = m1 + (size_t)B_ * NS;
    float* m2 = f1 + (size_t)B_ * NS;
    float* f2 = m2 + (size_t)B_ * NR;
    float2* rowP = (float2*)(f2 + (size_t)B_ * NR);
    float2* colP = rowP + (size_t)B_ * NS * 2;
    char* X0 = (char*)(colP + (size_t)B_ * NR * 4);
    unsigned short* imgT = (unsigned short*)X0;
    unsigned short* w1g  = (unsigned short*)(X0 + (size_t)B_ * DD * NR * 2);
    unsigned short* spT  = (unsigned short*)X0;
    unsigned short* w2g  = (unsigned short*)(X0 + (size_t)B_ * DD * NS * 2);
    const size_t NEED = (size_t)(X0 - base) + (size_t)B_ * DD * NS * 2 + (size_t)B_ * NS * NR * 2;
    const int wsok = (ws_size >= NEED) ? 1 : 0;

    zero_ws<<<dim3(1), dim3(64), 0, stream>>>(wsum);
    att_mfma<<<dim3(NR / 128, NS / 128, B_), dim3(512), 0, stream>>>(
        span, image, smask, imask, att, rowP, colP, wsok);

    if (wsok) {
        combine_stats<<<dim3((B_ * NS + B_ * NR) / 256), dim3(256), 0, stream>>>(
            rowP, colP, smask, imask, m1, f1, m2, f2);
        transpose_swz<<<dim3(DD / 32, NR / 32, B_), dim3(256), 0, stream>>>(image, imgT, NR);
        build_w12<<<dim3(NR / 64, NS / 64, B_), dim3(256), 0, stream>>>(
            att, smask, imask, m1, f1, m2, f2, w1g, w2g);
        gemm_apply<NR, NS, true, 0><<<dim3(DD / 256, NS / 64, B_), dim3(256), 0, stream>>>(
            w1g, imgT, span, att_first, wsum);
        transpose_swz<<<dim3(DD / 32, NS / 32, B_), dim3(256), 0, stream>>>(span, spT, NS);
        gemm_apply<NS, NR, false, 1><<<dim3(DD / 256, NR / 64, B_), dim3(256), 0, stream>>>(
            w2g, spT, image, nullptr, wsum);
    } else {
        first_kernel<<<dim3(NS / 32, B_), dim3(256), 0, stream>>>(span, image, smask, imask, att, att_first, wsum);
        second_kernel<<<dim3(NR / 32, B_), dim3(256), 0, stream>>>(span, image, smask, imask, att, wsum);
    }
    score_kernel<<<dim3(1), dim3(64), 0, stream>>>(wsum, out);
}

// Round 12
// 287.529 us; speedup vs baseline: 1.1742x; 1.1027x over previous
//
#include <hip/hip_runtime.h>
#include <hip/hip_bf16.h>
#include <math.h>

#define B_  64
#define NS  512
#define NR  256
#define DD  1024
#define NEGV (-1e10f)

typedef __attribute__((ext_vector_type(4))) float f32x4;
typedef __attribute__((ext_vector_type(8))) short bf16x8;

__device__ __forceinline__ unsigned short f2bf(float x) {
    unsigned u = __builtin_bit_cast(unsigned, x);
    unsigned r = u + 0x7FFFu + ((u >> 16) & 1u);
    return (unsigned short)(r >> 16);
}
// packed bf16 convert: D.lo = bf16(x), D.hi = bf16(y)
__device__ __forceinline__ unsigned pk2(float x, float y) {
    unsigned r;
    asm("v_cvt_pk_bf16_f32 %0, %1, %2" : "=v"(r) : "v"(x), "v"(y));
    return r;
}
// async global->LDS, 16B per lane
__device__ __forceinline__ void gload16(const void* g, void* l) {
    __builtin_amdgcn_global_load_lds((const __attribute__((address_space(1))) void*)g,
                                     (__attribute__((address_space(3))) void*)l, 16, 0, 0);
}

// ---------------------------------------------------------------- zero ws
__global__ __launch_bounds__(64) void zero_ws(double* ws) {
    if (threadIdx.x == 0) { ws[0] = 0.0; ws[1] = 0.0; }
}

// ================================================================ stage 1
// att = masked span @ image^T, single-pass bf16 MFMA, 128x128 tile, 512 thr.
// Double-buffered LDS (2x20KB) + 1-deep register prefetch, ONE barrier per
// K-step (reg-destined global loads stay in flight across barriers).
// Linear grid id = b + 64*y + 256*x -> all 8 blocks of batch b on one XCD
// (3MB/batch working set fits the 4MB per-XCD L2).
__global__ __launch_bounds__(512) void att_mfma(
    const float* __restrict__ span, const float* __restrict__ image,
    const int* __restrict__ smask, const int* __restrict__ imask,
    float* __restrict__ att, float2* __restrict__ rowP, float2* __restrict__ colP,
    int doStats) {
    const int id = blockIdx.x;
    const int b  = id & 63;
    const int ys = (id >> 6) & 3;     // s-tile
    const int xr = id >> 8;           // r-tile
    const int s0 = ys * 128;
    const int r0 = xr * 128;
    __shared__ unsigned short Abuf[2][128][40], Bbuf[2][128][40];   // 40KB
    const int tid  = threadIdx.x;
    const int lane = tid & 63;
    const int w    = tid >> 6;        // 0..7
    const int wso  = (w >> 2) * 64;   // s-half
    const int wro  = (w & 3) * 32;    // r-quarter
    const float* Sp = span  + ((size_t)b * NS + s0) * DD;
    const float* Im = image + ((size_t)b * NR + r0) * DD;

    f32x4 acc[4][2];
    #pragma unroll
    for (int i = 0; i < 4; ++i)
        #pragma unroll
        for (int j = 0; j < 2; ++j) acc[i][j] = (f32x4){0.f, 0.f, 0.f, 0.f};

    const int row0 = tid >> 2;        // 0..127 (one row per thread)
    const int kq   = (tid & 3) * 8;   // 0,8,16,24
    const int fr   = lane & 15;
    const int fq   = lane >> 4;
    const int fk   = fq * 8;

    float4 ra[4], rb[4];              // [0,1]=A row, [2,3]=B row
    auto LOADR = [&](float4* r, int k0) {
        r[0] = *reinterpret_cast<const float4*>(Sp + (size_t)row0 * DD + k0 + kq);
        r[1] = *reinterpret_cast<const float4*>(Sp + (size_t)row0 * DD + k0 + kq + 4);
        r[2] = *reinterpret_cast<const float4*>(Im + (size_t)row0 * DD + k0 + kq);
        r[3] = *reinterpret_cast<const float4*>(Im + (size_t)row0 * DD + k0 + kq + 4);
    };
    auto CVTW = [&](const float4* r, int buf) {
        uint4 u;
        u.x = pk2(r[0].x, r[0].y); u.y = pk2(r[0].z, r[0].w);
        u.z = pk2(r[1].x, r[1].y); u.w = pk2(r[1].z, r[1].w);
        *reinterpret_cast<uint4*>(&Abuf[buf][row0][kq]) = u;
        u.x = pk2(r[2].x, r[2].y); u.y = pk2(r[2].z, r[2].w);
        u.z = pk2(r[3].x, r[3].y); u.w = pk2(r[3].z, r[3].w);
        *reinterpret_cast<uint4*>(&Bbuf[buf][row0][kq]) = u;
    };
    auto MFMAS = [&](int buf) {
        bf16x8 ah[4], bh[2];
        #pragma unroll
        for (int mf = 0; mf < 4; ++mf)
            ah[mf] = *reinterpret_cast<const bf16x8*>(&Abuf[buf][wso + mf * 16 + fr][fk]);
        #pragma unroll
        for (int nf = 0; nf < 2; ++nf)
            bh[nf] = *reinterpret_cast<const bf16x8*>(&Bbuf[buf][wro + nf * 16 + fr][fk]);
        #pragma unroll
        for (int mf = 0; mf < 4; ++mf)
            #pragma unroll
            for (int nf = 0; nf < 2; ++nf)
                acc[mf][nf] = __builtin_amdgcn_mfma_f32_16x16x32_bf16(ah[mf], bh[nf], acc[mf][nf], 0, 0, 0);
    };

    // prologue: step0 staged in buf0; step1 data in flight (rb)
    LOADR(ra, 0);
    CVTW(ra, 0);
    LOADR(rb, 32);
    __syncthreads();
    for (int kk = 0; kk < 16; ++kk) {
        const int k = kk * 2;
        // even step k: consume buf0; prefetch step k+2 into ra; stage step k+1 (rb) -> buf1
        if (k + 2 < 32) LOADR(ra, (k + 2) * 32);
        MFMAS(0);
        CVTW(rb, 1);
        __syncthreads();
        // odd step k+1: consume buf1; prefetch step k+3 into rb; stage step k+2 (ra) -> buf0
        if (k + 3 < 32) LOADR(rb, (k + 3) * 32);
        MFMAS(1);
        if (k + 2 < 32) CVTW(ra, 0);
        __syncthreads();
    }

    // ---- epilogue: mask + zero->NEG store + fused exp softmax partial stats
    float2* rowLDS = reinterpret_cast<float2*>(&Abuf[0][0][0]);   // [128][4]
    float2* colLDS = rowLDS + 512;                                // [128][2]
    int imv[2];
    #pragma unroll
    for (int nf = 0; nf < 2; ++nf) imv[nf] = imask[b * NR + r0 + wro + nf * 16 + fr];
    float cmax[2] = {-3.4e38f, -3.4e38f};
    float smv[4][4];
    #pragma unroll
    for (int mf = 0; mf < 4; ++mf) {
        #pragma unroll
        for (int i = 0; i < 4; ++i) {
            const int s = s0 + wso + mf * 16 + fq * 4 + i;
            const int sm = smask[b * NS + s];
            smv[mf][i] = (float)sm;
            float* orow = att + ((size_t)b * NS + s) * NR + r0 + wro;
            float vj[2];
            #pragma unroll
            for (int nf = 0; nf < 2; ++nf) {
                float v = acc[mf][nf][i] * (float)(sm * imv[nf]);
                v = (v != 0.0f) ? v : NEGV;
                orow[nf * 16 + fr] = v;
                vj[nf] = v;
                cmax[nf] = fmaxf(cmax[nf], v);
            }
            if (doStats) {
                float rm = fmaxf(vj[0], vj[1]);
                rm = fmaxf(rm, __shfl_xor(rm, 1));
                rm = fmaxf(rm, __shfl_xor(rm, 2));
                rm = fmaxf(rm, __shfl_xor(rm, 4));
                rm = fmaxf(rm, __shfl_xor(rm, 8));
                float rs = __expf(vj[0] - rm) + __expf(vj[1] - rm);
                rs += __shfl_xor(rs, 1);
                rs += __shfl_xor(rs, 2);
                rs += __shfl_xor(rs, 4);
                rs += __shfl_xor(rs, 8);
                if (fr == 0) rowLDS[(wso + mf * 16 + fq * 4 + i) * 4 + (w & 3)] = make_float2(rm, rs);
            }
        }
    }
    if (doStats) {
        #pragma unroll
        for (int nf = 0; nf < 2; ++nf) {
            cmax[nf] = fmaxf(cmax[nf], __shfl_xor(cmax[nf], 16));
            cmax[nf] = fmaxf(cmax[nf], __shfl_xor(cmax[nf], 32));
        }
        float csum[2] = {0.f, 0.f};
        #pragma unroll
        for (int mf = 0; mf < 4; ++mf)
            #pragma unroll
            for (int i = 0; i < 4; ++i)
                #pragma unroll
                for (int nf = 0; nf < 2; ++nf) {
                    float v = acc[mf][nf][i] * (smv[mf][i] * (float)imv[nf]);
                    v = (v != 0.0f) ? v : NEGV;
                    csum[nf] += __expf(v - cmax[nf]);
                }
        #pragma unroll
        for (int nf = 0; nf < 2; ++nf) {
            csum[nf] += __shfl_xor(csum[nf], 16);
            csum[nf] += __shfl_xor(csum[nf], 32);
        }
        if (lane < 16) {
            #pragma unroll
            for (int nf = 0; nf < 2; ++nf)
                colLDS[(wro + nf * 16 + lane) * 2 + (w >> 2)] = make_float2(cmax[nf], csum[nf]);
        }
        __syncthreads();
        if (tid < 128) {
            float2 q0 = rowLDS[tid * 4 + 0], q1 = rowLDS[tid * 4 + 1];
            float2 q2 = rowLDS[tid * 4 + 2], q3 = rowLDS[tid * 4 + 3];
            const float m = fmaxf(fmaxf(q0.x, q1.x), fmaxf(q2.x, q3.x));
            const float ssum = q0.y * __expf(q0.x - m) + q1.y * __expf(q1.x - m)
                             + q2.y * __expf(q2.x - m) + q3.y * __expf(q3.x - m);
            rowP[((size_t)b * NS + s0 + tid) * 2 + xr] = make_float2(m, ssum);
        } else if (tid < 256) {
            const int c = tid - 128;
            const float2 q0 = colLDS[c * 2 + 0], q1 = colLDS[c * 2 + 1];
            const float m = fmaxf(q0.x, q1.x);
            const float ssum = q0.y * __expf(q0.x - m) + q1.y * __expf(q1.x - m);
            colP[((size_t)b * NR + r0 + c) * 4 + ys] = make_float2(m, ssum);
        }
    }
}

// ================================================================ combine partials -> m1,f1 (rows), m2,f2 (cols)   [r4-verbatim]
__global__ __launch_bounds__(256) void combine_stats(
    const float2* __restrict__ rowP, const float2* __restrict__ colP,
    const int* __restrict__ smask, const int* __restrict__ imask,
    float* __restrict__ m1, float* __restrict__ f1,
    float* __restrict__ m2, float* __restrict__ f2) {
    const int idx = blockIdx.x * 256 + threadIdx.x;
    if (idx < B_ * NS) {
        const float2 p0 = rowP[(size_t)idx * 2 + 0];
        const float2 p1 = rowP[(size_t)idx * 2 + 1];
        const float m = fmaxf(p0.x, p1.x);
        const float s = p0.y * __expf(p0.x - m) + p1.y * __expf(p1.x - m);
        m1[idx] = m;
        f1[idx] = (float)smask[idx] / s;
    } else if (idx < B_ * NS + B_ * NR) {
        const int j = idx - B_ * NS;
        const float2 p0 = colP[(size_t)j * 4 + 0];
        const float2 p1 = colP[(size_t)j * 4 + 1];
        const float2 p2 = colP[(size_t)j * 4 + 2];
        const float2 p3 = colP[(size_t)j * 4 + 3];
        const float m = fmaxf(fmaxf(p0.x, p1.x), fmaxf(p2.x, p3.x));
        const float s = p0.y * __expf(p0.x - m) + p1.y * __expf(p1.x - m)
                      + p2.y * __expf(p2.x - m) + p3.y * __expf(p3.x - m);
        m2[j] = m;
        f2[j] = (float)imask[j] / s;
    }
}

// ================================================================ transpose f32 -> bf16, K-swizzled within 64-chunks by (d&7)<<3  [r4-verbatim]
__global__ __launch_bounds__(256) void transpose_swz(
    const float* __restrict__ src, unsigned short* __restrict__ dst, int N) {
    const int b = blockIdx.z, n0 = blockIdx.y * 32, d0 = blockIdx.x * 32;
    __shared__ unsigned short T[32][36];
    const int t = threadIdx.x;
    {
        const int n = t >> 3, dq = (t & 7) * 4;
        const float4 v = *reinterpret_cast<const float4*>(src + ((size_t)b * N + n0 + n) * DD + d0 + dq);
        T[dq + 0][n] = f2bf(v.x); T[dq + 1][n] = f2bf(v.y);
        T[dq + 2][n] = f2bf(v.z); T[dq + 3][n] = f2bf(v.w);
    }
    __syncthreads();
    {
        const int d = t >> 3, nq = (t & 7) * 4;
        const int dg = d0 + d;
        const int base = n0 + nq;
        const int pos = (base & 63) ^ ((dg & 7) << 3);
        const size_t idx = ((size_t)b * DD + dg) * N + (base & ~63) + pos;
        *reinterpret_cast<ushort4*>(dst + idx) = *reinterpret_cast<const ushort4*>(&T[d][nq]);
    }
}

// ================================================================ build w1 ([s][r], swizzled) AND w2 ([r][s], swizzled) in one att pass  [r4-verbatim]
__global__ __launch_bounds__(256) void build_w12(
    const float* __restrict__ att, const int* __restrict__ smask,
    const int* __restrict__ imask,
    const float* __restrict__ m1, const float* __restrict__ f1,
    const float* __restrict__ m2, const float* __restrict__ f2,
    unsigned short* __restrict__ w1g, unsigned short* __restrict__ w2g) {
    const int b = blockIdx.z, s0 = blockIdx.y * 64, r0 = blockIdx.x * 64;
    __shared__ unsigned short T[64][68];
    __shared__ float m2s[64], f2s[64], ims[64];
    const int tid = threadIdx.x;
    if (tid < 64) {
        m2s[tid] = m2[b * NR + r0 + tid];
        f2s[tid] = f2[b * NR + r0 + tid];
        ims[tid] = (float)imask[b * NR + r0 + tid];
    }
    __syncthreads();
    {
        const int srow = tid >> 2, rg = (tid & 3) * 16;
        const int s = s0 + srow;
        const float m1v = m1[b * NS + s], f1v = f1[b * NS + s];
        const float smv = (float)smask[b * NS + s];
        const float* arow = att + ((size_t)b * NS + s) * NR + r0;
        const int w1swz = (s & 7) << 3;
        unsigned short* w1row = w1g + ((size_t)b * NS + s) * NR + r0;
        #pragma unroll
        for (int g = 0; g < 4; ++g) {
            const int rr = rg + g * 4;
            const float4 a = *reinterpret_cast<const float4*>(arow + rr);
            const float e0 = __expf(a.x - m1v) * f1v * ims[rr + 0];
            const float e1 = __expf(a.y - m1v) * f1v * ims[rr + 1];
            const float e2 = __expf(a.z - m1v) * f1v * ims[rr + 2];
            const float e3 = __expf(a.w - m1v) * f1v * ims[rr + 3];
            uint2 u; u.x = pk2(e0, e1); u.y = pk2(e2, e3);
            *reinterpret_cast<uint2*>(w1row + (rr ^ w1swz)) = u;
            const float q0 = __expf(a.x - m2s[rr + 0]) * f2s[rr + 0] * smv;
            const float q1 = __expf(a.y - m2s[rr + 1]) * f2s[rr + 1] * smv;
            const float q2 = __expf(a.z - m2s[rr + 2]) * f2s[rr + 2] * smv;
            const float q3 = __expf(a.w - m2s[rr + 3]) * f2s[rr + 3] * smv;
            const unsigned t0 = pk2(q0, q1), t1 = pk2(q2, q3);
            T[rr + 0][srow] = (unsigned short)(t0 & 0xFFFF);
            T[rr + 1][srow] = (unsigned short)(t0 >> 16);
            T[rr + 2][srow] = (unsigned short)(t1 & 0xFFFF);
            T[rr + 3][srow] = (unsigned short)(t1 >> 16);
        }
    }
    __syncthreads();
    {
        const int rl = tid >> 2, sg = (tid & 3) * 16;
        const int w2swz = (rl & 7) << 3;
        unsigned short* w2row = w2g + ((size_t)b * NR + r0 + rl) * NS + s0;
        #pragma unroll
        for (int g = 0; g < 4; ++g) {
            const int ss = sg + g * 4;
            *reinterpret_cast<ushort4*>(w2row + (ss ^ w2swz)) =
                *reinterpret_cast<const ushort4*>(&T[rl][ss]);
        }
    }
}

// ================================================================ apply GEMM [r4-verbatim]: C[64 m x 256 d] = A[m][K] @ Bt[d][K]
template<int KTOT, int MT, bool WOUT, int WIDX>
__global__ __launch_bounds__(256) void gemm_apply(
    const unsigned short* __restrict__ Ag, const unsigned short* __restrict__ Btg,
    const float* __restrict__ ref, float* __restrict__ outp, double* __restrict__ wsum) {
    const int b = blockIdx.z, m0 = blockIdx.y * 64, d0 = blockIdx.x * 256;
    __shared__ unsigned short As[64 * 64];
    __shared__ unsigned short Bs[256 * 64];
    __shared__ float redsum[256];
    const int tid = threadIdx.x, lane = tid & 63, w = tid >> 6;
    const int fr = lane & 15, fq = lane >> 4;
    f32x4 acc[4][4];
    #pragma unroll
    for (int i = 0; i < 4; ++i)
        #pragma unroll
        for (int j = 0; j < 4; ++j) acc[i][j] = (f32x4){0.f, 0.f, 0.f, 0.f};

    const int srow = tid >> 3;             // 0..31 staging row
    const int scol = (tid & 7) * 16;       // byte offset in 128B chunk
    for (int kc = 0; kc < KTOT / 64; ++kc) {
        const char* asrc = (const char*)(Ag + ((size_t)b * MT + m0) * KTOT) + kc * 128 + scol;
        #pragma unroll
        for (int c = 0; c < 2; ++c)
            gload16(asrc + (size_t)(c * 32 + srow) * (KTOT * 2), (char*)As + (c * 256 + tid) * 16);
        const char* bsrc = (const char*)(Btg + ((size_t)b * DD + d0) * KTOT) + kc * 128 + scol;
        #pragma unroll
        for (int c = 0; c < 8; ++c)
            gload16(bsrc + (size_t)(c * 32 + srow) * (KTOT * 2), (char*)Bs + (c * 256 + tid) * 16);
        __syncthreads();
        #pragma unroll
        for (int ks = 0; ks < 2; ++ks) {
            bf16x8 aF[4], bF[4];
            #pragma unroll
            for (int mf = 0; mf < 4; ++mf) {
                const int row = mf * 16 + fr;
                const int pos = (ks * 32 + fq * 8) ^ ((row & 7) << 3);
                aF[mf] = *reinterpret_cast<const bf16x8*>(&As[row * 64 + pos]);
            }
            #pragma unroll
            for (int nf = 0; nf < 4; ++nf) {
                const int row = w * 64 + nf * 16 + fr;
                const int pos = (ks * 32 + fq * 8) ^ ((row & 7) << 3);
                bF[nf] = *reinterpret_cast<const bf16x8*>(&Bs[row * 64 + pos]);
            }
            #pragma unroll
            for (int mf = 0; mf < 4; ++mf)
                #pragma unroll
                for (int nf = 0; nf < 4; ++nf)
                    acc[mf][nf] = __builtin_amdgcn_mfma_f32_16x16x32_bf16(aF[mf], bF[nf], acc[mf][nf], 0, 0, 0);
        }
        __syncthreads();
    }
    float sumsq = 0.0f;
    #pragma unroll
    for (int mf = 0; mf < 4; ++mf) {
        #pragma unroll
        for (int i = 0; i < 4; ++i) {
            const int row = m0 + mf * 16 + fq * 4 + i;
            const size_t base = ((size_t)b * MT + row) * DD + d0 + w * 64;
            #pragma unroll
            for (int nf = 0; nf < 4; ++nf) {
                const float v = acc[mf][nf][i];
                const float rv = ref[base + nf * 16 + fr];
                if constexpr (WOUT) outp[base + nf * 16 + fr] = v;
                const float dx = rv - v;
                sumsq += dx * dx;
            }
        }
    }
    redsum[tid] = sumsq; __syncthreads();
    for (int off = 128; off; off >>= 1) {
        if (tid < off) redsum[tid] += redsum[tid + off];
        __syncthreads();
    }
    if (tid == 0) atomicAdd(wsum + WIDX, (double)redsum[0]);
}

// ================================================================ fallback f32 kernels (used when ws too small)
__global__ __launch_bounds__(256) void first_kernel(
    const float* __restrict__ span, const float* __restrict__ image,
    const int* __restrict__ smask, const int* __restrict__ imask,
    const float* __restrict__ att, float* __restrict__ att_first,
    double* __restrict__ ws) {
    const int b  = blockIdx.y;
    const int s0 = blockIdx.x * 32;
    __shared__ float wT[256][36];
    __shared__ float Is[32][132];
    __shared__ float red[256];
    const int tid  = threadIdx.x;
    const int lane = tid & 63, wave = tid >> 6;
    for (int i = 0; i < 8; ++i) {
        const int srel = wave * 8 + i;
        const int s    = s0 + srel;
        const float4 v = *reinterpret_cast<const float4*>(att + ((size_t)b * NS + s) * NR + lane * 4);
        float m = fmaxf(fmaxf(v.x, v.y), fmaxf(v.z, v.w));
        #pragma unroll
        for (int off = 32; off; off >>= 1) m = fmaxf(m, __shfl_xor(m, off));
        float4 e;
        e.x = expf(v.x - m); e.y = expf(v.y - m); e.z = expf(v.z - m); e.w = expf(v.w - m);
        float sum = e.x + e.y + e.z + e.w;
        #pragma unroll
        for (int off = 32; off; off >>= 1) sum += __shfl_xor(sum, off);
        const float fac = (float)smask[b * NS + s] / sum;
        const int4 im4 = *reinterpret_cast<const int4*>(imask + b * NR + lane * 4);
        wT[lane * 4 + 0][srel] = e.x * fac * (float)im4.x;
        wT[lane * 4 + 1][srel] = e.y * fac * (float)im4.y;
        wT[lane * 4 + 2][srel] = e.z * fac * (float)im4.z;
        wT[lane * 4 + 3][srel] = e.w * fac * (float)im4.w;
    }
    __syncthreads();
    float sumsq = 0.0f;
    const int txd = tid & 31;
    const int tys = tid >> 5;
    const float* Ib = image + (size_t)b * NR * DD;
    for (int dc = 0; dc < 8; ++dc) {
        const int d0 = dc * 128;
        float acc[4][4] = {};
        for (int rc = 0; rc < 8; ++rc) {
            const int r0 = rc * 32;
            {
                const int rr = tid >> 3;
                const int cb = tid & 7;
                const float* src = Ib + (size_t)(r0 + rr) * DD + d0;
                #pragma unroll
                for (int q = 0; q < 4; ++q)
                    *reinterpret_cast<float4*>(&Is[rr][(cb + 8 * q) * 4]) =
                        *reinterpret_cast<const float4*>(src + (cb + 8 * q) * 4);
            }
            __syncthreads();
            #pragma unroll 4
            for (int rr = 0; rr < 32; ++rr) {
                const float4 wv = *reinterpret_cast<const float4*>(&wT[r0 + rr][tys * 4]);
                const float4 iv = *reinterpret_cast<const float4*>(&Is[rr][txd * 4]);
                const float wvv[4] = {wv.x, wv.y, wv.z, wv.w};
                const float ivv[4] = {iv.x, iv.y, iv.z, iv.w};
                #pragma unroll
                for (int i = 0; i < 4; ++i)
                    #pragma unroll
                    for (int j = 0; j < 4; ++j)
                        acc[i][j] += wvv[i] * ivv[j];
            }
            __syncthreads();
        }
        #pragma unroll
        for (int i = 0; i < 4; ++i) {
            const int s = s0 + tys * 4 + i;
            const size_t base = ((size_t)b * NS + s) * DD + d0 + txd * 4;
            const float4 af = {acc[i][0], acc[i][1], acc[i][2], acc[i][3]};
            *reinterpret_cast<float4*>(att_first + base) = af;
            const float4 sp = *reinterpret_cast<const float4*>(span + base);
            float dx;
            dx = sp.x - af.x; sumsq += dx * dx;
            dx = sp.y - af.y; sumsq += dx * dx;
            dx = sp.z - af.z; sumsq += dx * dx;
            dx = sp.w - af.w; sumsq += dx * dx;
        }
    }
    red[tid] = sumsq; __syncthreads();
    for (int off = 128; off; off >>= 1) {
        if (tid < off) red[tid] += red[tid + off];
        __syncthreads();
    }
    if (tid == 0) atomicAdd(ws, (double)red[0]);
}

__global__ __launch_bounds__(256) void second_kernel(
    const float* __restrict__ span, const float* __restrict__ image,
    const int* __restrict__ smask, const int* __restrict__ imask,
    const float* __restrict__ att, double* __restrict__ ws) {
    const int b  = blockIdx.y;
    const int r0 = blockIdx.x * 32;
    __shared__ float w2s[32][36];
    __shared__ float Ss[32][132];
    __shared__ float mArr[32], fArr[32];
    __shared__ float redm[8][32];
    __shared__ float red[256];
    const int tid = threadIdx.x;
    const int rr = tid & 31, q = tid >> 5;
    const float* attb = att + (size_t)b * NS * NR + r0 + rr;
    float mloc = -3.4e38f;
    for (int t = 0; t < 64; ++t)
        mloc = fmaxf(mloc, attb[(size_t)(q * 64 + t) * NR]);
    redm[q][rr] = mloc;
    __syncthreads();
    if (tid < 32) {
        float m = redm[0][tid];
        #pragma unroll
        for (int qq = 1; qq < 8; ++qq) m = fmaxf(m, redm[qq][tid]);
        mArr[tid] = m;
    }
    __syncthreads();
    const float mcol = mArr[rr];
    float sloc = 0.0f;
    for (int t = 0; t < 64; ++t)
        sloc += expf(attb[(size_t)(q * 64 + t) * NR] - mcol);
    redm[q][rr] = sloc;
    __syncthreads();
    if (tid < 32) {
        float s = 0.0f;
        #pragma unroll
        for (int qq = 0; qq < 8; ++qq) s += redm[qq][tid];
        fArr[tid] = (float)imask[b * NR + r0 + tid] / s;
    }
    __syncthreads();
    float sumsq = 0.0f;
    const int txd = tid & 31;
    const int tyr = tid >> 5;
    const float* Sb = span + (size_t)b * NS * DD;
    for (int dc = 0; dc < 8; ++dc) {
        const int d0 = dc * 128;
        float acc[4][4] = {};
        for (int sc = 0; sc < 16; ++sc) {
            const int sb0 = sc * 32;
            {
                const int sr = tid >> 3;
                const int cb = tid & 7;
                const float* src = Sb + (size_t)(sb0 + sr) * DD + d0;
                #pragma unroll
                for (int qq = 0; qq < 4; ++qq)
                    *reinterpret_cast<float4*>(&Ss[sr][(cb + 8 * qq) * 4]) =
                        *reinterpret_cast<const float4*>(src + (cb + 8 * qq) * 4);
            }
            {
                const int ss = tid >> 3;
                const int rq = (tid & 7) * 4;
                const int s  = sb0 + ss;
                const float4 v = *reinterpret_cast<const float4*>(att + ((size_t)b * NS + s) * NR + r0 + rq);
                const float smv = (float)smask[b * NS + s];
                float4 wv;
                wv.x = expf(v.x - mArr[rq + 0]) * fArr[rq + 0] * smv;
                wv.y = expf(v.y - mArr[rq + 1]) * fArr[rq + 1] * smv;
                wv.z = expf(v.z - mArr[rq + 2]) * fArr[rq + 2] * smv;
                wv.w = expf(v.w - mArr[rq + 3]) * fArr[rq + 3] * smv;
                *reinterpret_cast<float4*>(&w2s[ss][rq]) = wv;
            }
            __syncthreads();
            #pragma unroll 4
            for (int ss = 0; ss < 32; ++ss) {
                const float4 wv = *reinterpret_cast<const float4*>(&w2s[ss][tyr * 4]);
                const float4 sv = *reinterpret_cast<const float4*>(&Ss[ss][txd * 4]);
                const float wvv[4] = {wv.x, wv.y, wv.z, wv.w};
                const float svv[4] = {sv.x, sv.y, sv.z, sv.w};
                #pragma unroll
                for (int i = 0; i < 4; ++i)
                    #pragma unroll
                    for (int j = 0; j < 4; ++j)
                        acc[i][j] += wvv[i] * svv[j];
            }
            __syncthreads();
        }
        #pragma unroll
        for (int i = 0; i < 4; ++i) {
            const int r = r0 + tyr * 4 + i;
            const float4 iv = *reinterpret_cast<const float4*>(image + ((size_t)b * NR + r) * DD + d0 + txd * 4);
            float dx;
            dx = iv.x - acc[i][0]; sumsq += dx * dx;
            dx = iv.y - acc[i][1]; sumsq += dx * dx;
            dx = iv.z - acc[i][2]; sumsq += dx * dx;
            dx = iv.w - acc[i][3]; sumsq += dx * dx;
        }
    }
    red[tid] = sumsq; __syncthreads();
    for (int off = 128; off; off >>= 1) {
        if (tid < off) red[tid] += red[tid + off];
        __syncthreads();
    }
    if (tid == 0) atomicAdd(ws + 1, (double)red[0]);
}

// ---------------------------------------------------------------- final score
__global__ __launch_bounds__(64) void score_kernel(const double* __restrict__ ws, float* __restrict__ out) {
    if (threadIdx.x == 0) {
        out[0] = (float)(ws[0] / (double)((size_t)B_ * NS * DD) +
                         ws[1] / (double)((size_t)B_ * NR * DD));
    }
}

extern "C" void kernel_launch(void* const* d_in, const int* in_sizes, int n_in,
                              void* d_out, int out_size, void* d_ws, size_t ws_size,
                              hipStream_t stream) {
    const float* span  = (const float*)d_in[0];
    const float* image = (const float*)d_in[1];
    const int*   smask = (const int*)d_in[2];
    const int*   imask = (const int*)d_in[3];
    float* out       = (float*)d_out;
    float* att_first = out + 1;
    float* att       = out + 1 + (size_t)B_ * NS * DD;

    // ws layout (r4):
    //  wsum(512B) | m1,f1 (B*NS f32 each) | m2,f2 (B*NR f32 each)
    //  | rowP (B*NS*2 float2) | colP (B*NR*4 float2)
    //  | X0: phase1 = { imgT (33.5M), w1 (16.8M) }
    //        phase2 = { spT [0,67.1M) } (overwrites imgT+w1 after gemm1)
    //        w2 at [67.1M, 83.9M)       (live from build_w12 to gemm2)
    char* base = (char*)d_ws;
    double* wsum = (double*)base;
    float* m1 = (float*)(base + 512);
    float* f1 = m1 + (size_t)B_ * NS;
    float* m2 = f1 + (size_t)B_ * NS;
    float* f2 = m2 + (size_t)B_ * NR;
    float2* rowP = (float2*)(f2 + (size_t)B_ * NR);
    float2* colP = rowP + (size_t)B_ * NS * 2;
    char* X0 = (char*)(colP + (size_t)B_ * NR * 4);
    unsigned short* imgT = (unsigned short*)X0;
    unsigned short* w1g  = (unsigned short*)(X0 + (size_t)B_ * DD * NR * 2);
    unsigned short* spT  = (unsigned short*)X0;
    unsigned short* w2g  = (unsigned short*)(X0 + (size_t)B_ * DD * NS * 2);
    const size_t NEED = (size_t)(X0 - base) + (size_t)B_ * DD * NS * 2 + (size_t)B_ * NS * NR * 2;
    const int wsok = (ws_size >= NEED) ? 1 : 0;

    zero_ws<<<dim3(1), dim3(64), 0, stream>>>(wsum);
    att_mfma<<<dim3(512), dim3(512), 0, stream>>>(
        span, image, smask, imask, att, rowP, colP, wsok);

    if (wsok) {
        combine_stats<<<dim3((B_ * NS + B_ * NR) / 256), dim3(256), 0, stream>>>(
            rowP, colP, smask, imask, m1, f1, m2, f2);
        transpose_swz<<<dim3(DD / 32, NR / 32, B_), dim3(256), 0, stream>>>(image, imgT, NR);
        build_w12<<<dim3(NR / 64, NS / 64, B_), dim3(256), 0, stream>>>(
            att, smask, imask, m1, f1, m2, f2, w1g, w2g);
        gemm_apply<NR, NS, true, 0><<<dim3(DD / 256, NS / 64, B_), dim3(256), 0, stream>>>(
            w1g, imgT, span, att_first, wsum);
        transpose_swz<<<dim3(DD / 32, NS / 32, B_), dim3(256), 0, stream>>>(span, spT, NS);
        gemm_apply<NS, NR, false, 1><<<dim3(DD / 256, NR / 64, B_), dim3(256), 0, stream>>>(
            w2g, spT, image, nullptr, wsum);
    } else {
        first_kernel<<<dim3(NS / 32, B_), dim3(256), 0, stream>>>(span, image, smask, imask, att, att_first, wsum);
        second_kernel<<<dim3(NR / 32, B_), dim3(256), 0, stream>>>(span, image, smask, imask, att, wsum);
    }
    score_kernel<<<dim3(1), dim3(64), 0, stream>>>(wsum, out);
}